// Round 2
// baseline (2313.087 us; speedup 1.0000x reference)
//
#include <hip/hip_runtime.h>
#include <cmath>
#include <cstdint>

#define NPOS 49
#define NANCH 588

// ---------------------------------------------------------------------------
// Weight transposes.
// w1t[c*256+o] = w1[o*512+c]                  (1x1 conv, [c][o])
// wNt[ck*256+o] = wN[o*2304+ck]               (3x3 convs, [c*9+k][o])
// wbt[ck*48+o], wct[ck*12+o]                  (heads)
// ---------------------------------------------------------------------------
__global__ void transpose_all(
    const float* __restrict__ w1, const float* __restrict__ w2,
    const float* __restrict__ w3, const float* __restrict__ w4,
    const float* __restrict__ wb, const float* __restrict__ wc,
    float* __restrict__ w1t, float* __restrict__ w2t, float* __restrict__ w3t,
    float* __restrict__ w4t, float* __restrict__ wbt, float* __restrict__ wct) {
  int idx = blockIdx.x * blockDim.x + threadIdx.x;
  if (idx < 131072) { int o = idx / 512, c = idx % 512; w1t[c * 256 + o] = w1[idx]; return; }
  idx -= 131072;
  if (idx < 589824) { int o = idx / 2304, ck = idx % 2304; w2t[ck * 256 + o] = w2[idx]; return; }
  idx -= 589824;
  if (idx < 589824) { int o = idx / 2304, ck = idx % 2304; w3t[ck * 256 + o] = w3[idx]; return; }
  idx -= 589824;
  if (idx < 589824) { int o = idx / 2304, ck = idx % 2304; w4t[ck * 256 + o] = w4[idx]; return; }
  idx -= 589824;
  if (idx < 110592) { int o = idx / 2304, ck = idx % 2304; wbt[ck * 48 + o] = wb[idx]; return; }
  idx -= 110592;
  if (idx < 27648)  { int o = idx / 2304, ck = idx % 2304; wct[ck * 12 + o] = wc[idx]; return; }
}

// ---------------------------------------------------------------------------
// conv 1x1 (512 -> 256) + bias + BN + ReLU.  1024 threads, 4-way K-split.
// ---------------------------------------------------------------------------
__global__ __launch_bounds__(1024, 4) void conv1x1_bn(
    const float* __restrict__ in, const float* __restrict__ wt,
    const float* __restrict__ bias, const float* __restrict__ gg,
    const float* __restrict__ be, const float* __restrict__ mu,
    const float* __restrict__ var, float* __restrict__ out) {
  __shared__ float smem[512 * 52];  // [512][52] tile; reused for partials
  const int b = blockIdx.x, t = threadIdx.x;
  const float* inb = in + (size_t)b * (512 * NPOS);
  for (int i = t; i < 512 * NPOS; i += 1024) {
    int c = i / NPOS, p = i - c * NPOS;
    smem[c * 52 + p] = inb[i];
  }
  __syncthreads();
  const int o = t & 255, cg = t >> 8, c0 = cg * 128;
  float acc[NPOS];
#pragma unroll
  for (int p = 0; p < NPOS; ++p) acc[p] = 0.f;
  float wcur = wt[c0 * 256 + o];
  for (int c = c0; c < c0 + 128; ++c) {
    int cn = (c + 1 < c0 + 128) ? c + 1 : c;
    float wnxt = wt[cn * 256 + o];  // prefetch
    const float4* tr = (const float4*)(smem + c * 52);
#pragma unroll
    for (int j = 0; j < 12; ++j) {
      float4 q = tr[j];
      acc[4 * j + 0] = fmaf(wcur, q.x, acc[4 * j + 0]);
      acc[4 * j + 1] = fmaf(wcur, q.y, acc[4 * j + 1]);
      acc[4 * j + 2] = fmaf(wcur, q.z, acc[4 * j + 2]);
      acc[4 * j + 3] = fmaf(wcur, q.w, acc[4 * j + 3]);
    }
    acc[48] = fmaf(wcur, smem[c * 52 + 48], acc[48]);
    wcur = wnxt;
  }
  __syncthreads();
  float* p0 = smem;
  float* p1 = smem + 12544;
  if (cg == 1) { for (int p = 0; p < NPOS; ++p) p0[o * NPOS + p] = acc[p]; }
  if (cg == 3) { for (int p = 0; p < NPOS; ++p) p1[o * NPOS + p] = acc[p]; }
  __syncthreads();
  if (cg == 0) { for (int p = 0; p < NPOS; ++p) acc[p] += p0[o * NPOS + p]; }
  if (cg == 2) { for (int p = 0; p < NPOS; ++p) acc[p] += p1[o * NPOS + p]; }
  __syncthreads();
  if (cg == 2) { for (int p = 0; p < NPOS; ++p) p0[o * NPOS + p] = acc[p]; }
  __syncthreads();
  if (cg == 0) {
    float scale = gg[o] / sqrtf(var[o] + 1e-5f);
    float add = (bias[o] - mu[o]) * scale + be[o];
#pragma unroll
    for (int p = 0; p < NPOS; ++p) {
      float v = (acc[p] + p0[o * NPOS + p]) * scale + add;
      p1[o * NPOS + p] = v > 0.f ? v : 0.f;
    }
  }
  __syncthreads();
  float* outb = out + (size_t)b * (256 * NPOS);
  for (int i = t; i < 256 * NPOS; i += 1024) outb[i] = p1[i];
}

// ---------------------------------------------------------------------------
// conv 3x3 pad1 (256 -> 256) + bias + BN + ReLU.  1024 threads, 4-way K-split.
// Rolling 3-row register buffer; all LDS reads are wave-broadcast b128.
// ---------------------------------------------------------------------------
#define LOADROW(dst, base, rr)                                          \
  do {                                                                  \
    const float4* q4_ = (const float4*)((base) + (rr) * 12);            \
    float4 q0_ = q4_[0], q1_ = q4_[1], q2_ = q4_[2];                    \
    dst[0] = q0_.x; dst[1] = q0_.y; dst[2] = q0_.z; dst[3] = q0_.w;     \
    dst[4] = q1_.x; dst[5] = q1_.y; dst[6] = q1_.z; dst[7] = q1_.w;     \
    dst[8] = q2_.x;                                                     \
  } while (0)

__global__ __launch_bounds__(1024, 4) void conv3x3_bn(
    const float* __restrict__ in, const float* __restrict__ wt,
    const float* __restrict__ bias, const float* __restrict__ gg,
    const float* __restrict__ be, const float* __restrict__ mu,
    const float* __restrict__ var, float* __restrict__ out) {
  __shared__ float smem[256 * 108];  // [c][9][12] padded tile
  const int b = blockIdx.x, t = threadIdx.x;
  for (int i = t; i < 256 * 108; i += 1024) smem[i] = 0.f;
  __syncthreads();
  const float* inb = in + (size_t)b * (256 * NPOS);
  for (int i = t; i < 256 * NPOS; i += 1024) {
    int c = i / NPOS, p = i - c * NPOS, y = p / 7, x = p - y * 7;
    smem[c * 108 + (y + 1) * 12 + (x + 1)] = inb[i];
  }
  __syncthreads();
  const int o = t & 255, cg = t >> 8, c0 = cg * 64;
  float acc[NPOS];
#pragma unroll
  for (int p = 0; p < NPOS; ++p) acc[p] = 0.f;
  for (int c = c0; c < c0 + 64; ++c) {
    float w[9];
#pragma unroll
    for (int k = 0; k < 9; ++k) w[k] = wt[(c * 9 + k) * 256 + o];
    const float* tb = smem + c * 108;
    float R[3][9];
    LOADROW(R[0], tb, 0);
    LOADROW(R[1], tb, 1);
#pragma unroll
    for (int y = 0; y < 7; ++y) {
      LOADROW(R[(y + 2) % 3], tb, y + 2);
      const float* r0 = R[y % 3];
      const float* r1 = R[(y + 1) % 3];
      const float* r2 = R[(y + 2) % 3];
#pragma unroll
      for (int x = 0; x < 7; ++x) {
        float s = acc[y * 7 + x];
        s = fmaf(w[0], r0[x], s);
        s = fmaf(w[1], r0[x + 1], s);
        s = fmaf(w[2], r0[x + 2], s);
        s = fmaf(w[3], r1[x], s);
        s = fmaf(w[4], r1[x + 1], s);
        s = fmaf(w[5], r1[x + 2], s);
        s = fmaf(w[6], r2[x], s);
        s = fmaf(w[7], r2[x + 1], s);
        s = fmaf(w[8], r2[x + 2], s);
        acc[y * 7 + x] = s;
      }
    }
  }
  __syncthreads();
  float* p0 = smem;
  float* p1 = smem + 12544;
  if (cg == 1) { for (int p = 0; p < NPOS; ++p) p0[o * NPOS + p] = acc[p]; }
  if (cg == 3) { for (int p = 0; p < NPOS; ++p) p1[o * NPOS + p] = acc[p]; }
  __syncthreads();
  if (cg == 0) { for (int p = 0; p < NPOS; ++p) acc[p] += p0[o * NPOS + p]; }
  if (cg == 2) { for (int p = 0; p < NPOS; ++p) acc[p] += p1[o * NPOS + p]; }
  __syncthreads();
  if (cg == 2) { for (int p = 0; p < NPOS; ++p) p0[o * NPOS + p] = acc[p]; }
  __syncthreads();
  if (cg == 0) {
    float scale = gg[o] / sqrtf(var[o] + 1e-5f);
    float add = (bias[o] - mu[o]) * scale + be[o];
#pragma unroll
    for (int p = 0; p < NPOS; ++p) {
      float v = (acc[p] + p0[o * NPOS + p]) * scale + add;
      p1[o * NPOS + p] = v > 0.f ? v : 0.f;
    }
  }
  __syncthreads();
  float* outb = out + (size_t)b * (256 * NPOS);
  for (int i = t; i < 256 * NPOS; i += 1024) outb[i] = p1[i];
}

// ---------------------------------------------------------------------------
// Heads (box 48ch + cls 12ch, 3x3 pad1) + decode + sigmoid.
// 512 threads: 60 out-ch x 8-way K-split.  Writes BX[588*4], SC[588] per img.
// ---------------------------------------------------------------------------
__global__ __launch_bounds__(512, 2) void heads_decode(
    const float* __restrict__ in, const float* __restrict__ wbt,
    const float* __restrict__ wct, const float* __restrict__ bb,
    const float* __restrict__ bc, float* __restrict__ BXg,
    float* __restrict__ SCg) {
  __shared__ float smem[256 * 108];
  const int b = blockIdx.x, t = threadIdx.x;
  for (int i = t; i < 256 * 108; i += 512) smem[i] = 0.f;
  __syncthreads();
  const float* inb = in + (size_t)b * (256 * NPOS);
  for (int i = t; i < 256 * NPOS; i += 512) {
    int c = i / NPOS, p = i - c * NPOS, y = p / 7, x = p - y * 7;
    smem[c * 108 + (y + 1) * 12 + (x + 1)] = inb[i];
  }
  __syncthreads();
  float acc[NPOS];
#pragma unroll
  for (int p = 0; p < NPOS; ++p) acc[p] = 0.f;
  int o = 0, cg = 0;
  if (t < 480) {
    o = t % 60; cg = t / 60;  // 8-way K-split, 32 c each
    const float* wbase; int wstr;
    if (o < 48) { wbase = wbt + o; wstr = 48; }
    else        { wbase = wct + (o - 48); wstr = 12; }
    const int c0 = cg * 32;
    for (int c = c0; c < c0 + 32; ++c) {
      float w[9];
#pragma unroll
      for (int k = 0; k < 9; ++k) w[k] = wbase[(c * 9 + k) * wstr];
      const float* tb = smem + c * 108;
      float R[3][9];
      LOADROW(R[0], tb, 0);
      LOADROW(R[1], tb, 1);
#pragma unroll
      for (int y = 0; y < 7; ++y) {
        LOADROW(R[(y + 2) % 3], tb, y + 2);
        const float* r0 = R[y % 3];
        const float* r1 = R[(y + 1) % 3];
        const float* r2 = R[(y + 2) % 3];
#pragma unroll
        for (int x = 0; x < 7; ++x) {
          float s = acc[y * 7 + x];
          s = fmaf(w[0], r0[x], s);
          s = fmaf(w[1], r0[x + 1], s);
          s = fmaf(w[2], r0[x + 2], s);
          s = fmaf(w[3], r1[x], s);
          s = fmaf(w[4], r1[x + 1], s);
          s = fmaf(w[5], r1[x + 2], s);
          s = fmaf(w[6], r2[x], s);
          s = fmaf(w[7], r2[x + 1], s);
          s = fmaf(w[8], r2[x + 2], s);
          acc[y * 7 + x] = s;
        }
      }
    }
  }
  __syncthreads();
  float* part = smem;            // [7][60][49]
  float* H = smem + 7 * 2940;    // [60][49]
  if (t < 480 && cg > 0) {
#pragma unroll
    for (int p = 0; p < NPOS; ++p) part[(cg - 1) * 2940 + o * NPOS + p] = acc[p];
  }
  __syncthreads();
  if (t < 60) {  // cg == 0
    float bsum = (o < 48) ? bb[o] : bc[o - 48];
#pragma unroll
    for (int p = 0; p < NPOS; ++p) {
      float v = acc[p] + bsum;
      for (int g = 0; g < 7; ++g) v += part[g * 2940 + o * NPOS + p];
      H[o * NPOS + p] = v;
    }
  }
  __syncthreads();
  const float scl[4] = {0.3f, 0.5f, 0.7f, 0.9f};
  const float rat[3] = {0.7f, 1.0f, 1.3f};
  for (int n = t; n < NANCH; n += 512) {
    int p = n / 12, a = n - p * 12;
    int ph = p / 7, pw = p - ph * 7;
    float cx = (ph + 0.5f) / 7.0f;
    float cy = (pw + 0.5f) / 7.0f;
    int s = a / 3, r = a - s * 3;
    float rt = sqrtf(rat[r]);
    float wsz = scl[s] * rt, hsz = scl[s] / rt;
    float x1 = cx + (-wsz) * 0.5f, y1 = cy + (-hsz) * 0.5f;
    float x2 = cx + wsz * 0.5f,    y2 = cy + hsz * 0.5f;
    float acx = (x1 + x2) * 0.5f,  acy = (y1 + y2) * 0.5f;
    float asx = x2 - x1,           asy = y2 - y1;
    float bp0 = H[(a * 4 + 0) * NPOS + p];
    float bp1 = H[(a * 4 + 1) * NPOS + p];
    float bp2 = H[(a * 4 + 2) * NPOS + p];
    float bp3 = H[(a * 4 + 3) * NPOS + p];
    float pcx = bp0 * asx + acx;
    float pcy = bp1 * asy + acy;
    float psx = expf(bp2) * asx;
    float psy = expf(bp3) * asy;
    float* bx = BXg + (size_t)b * (NANCH * 4) + n * 4;
    bx[0] = pcx - psx * 0.5f;
    bx[1] = pcy - psy * 0.5f;
    bx[2] = pcx + psx * 0.5f;
    bx[3] = pcy + psy * 0.5f;
    float lg = H[(48 + a) * NPOS + p];
    SCg[(size_t)b * NANCH + n] = 1.0f / (1.0f + expf(-lg));
  }
}

// ---------------------------------------------------------------------------
// NMS: rank sort + IoU bitmask + wave-parallel greedy scan.  512 thr, 66 KB.
// ---------------------------------------------------------------------------
__device__ inline unsigned long long shfl64(unsigned long long v, int lane) {
  int lo = __shfl((int)(unsigned)(v & 0xffffffffULL), lane, 64);
  int hi = __shfl((int)(unsigned)(v >> 32), lane, 64);
  return ((unsigned long long)(unsigned)hi << 32) | (unsigned)lo;
}

__global__ __launch_bounds__(512, 4) void nms_kernel(
    const float* __restrict__ BXg, const float* __restrict__ SCg,
    float* __restrict__ out) {
  __shared__ float smem[16576];
  unsigned long long* KEY = (unsigned long long*)smem;          // [588]
  float* SB  = smem + 1176;                                     // [588*4]
  float* SSc = smem + 3528;                                     // [588]
  float* AR  = smem + 4116;                                     // [588]
  unsigned long long* ADJ = (unsigned long long*)(smem + 4704); // [588*10]
  int* KEEP = (int*)(smem + 16464);                             // [100]
  int* CNT  = (int*)(smem + 16564);
  const int b = blockIdx.x, t = threadIdx.x;
  const float* scb = SCg + (size_t)b * NANCH;
  const float4* bxb = (const float4*)(BXg + (size_t)b * (NANCH * 4));
  // phase 1: build sort keys (score desc, idx asc)
  for (int i = t; i < NANCH; i += 512) {
    unsigned u = __float_as_uint(scb[i]);
    u = (u & 0x80000000u) ? ~u : (u | 0x80000000u);
    u = ~u;
    KEY[i] = ((unsigned long long)u << 32) | (unsigned)i;
  }
  __syncthreads();
  // phase 2: rank + scatter into sorted arrays
  for (int i = t; i < NANCH; i += 512) {
    unsigned long long k = KEY[i];
    int rank = 0;
    for (int j = 0; j < NANCH; ++j) rank += (KEY[j] < k) ? 1 : 0;
    float4 bx = bxb[i];
    ((float4*)SB)[rank] = bx;
    SSc[rank] = scb[i];
    AR[rank] = (bx.z - bx.x) * (bx.w - bx.y);
  }
  __syncthreads();
  // phase 3: IoU adjacency bitmask over sorted order; task = (row, word)
  const float4* SB4 = (const float4*)SB;
  for (int task = t; task < NANCH * 10; task += 512) {
    int i = task % NANCH, w = task / NANCH;
    float4 a = SB4[i];
    float aar = AR[i];
    int jbase = w * 64;
    int jend = NANCH - jbase; if (jend > 64) jend = 64;
    unsigned long long bits = 0;
    for (int bi = 0; bi < jend; ++bi) {
      int j = jbase + bi;
      float4 bb = SB4[j];
      float ltx = fmaxf(a.x, bb.x), lty = fmaxf(a.y, bb.y);
      float rbx = fminf(a.z, bb.z), rby = fminf(a.w, bb.w);
      float wx = rbx - ltx; wx = wx > 0.f ? wx : 0.f;
      float wy = rby - lty; wy = wy > 0.f ? wy : 0.f;
      float inter = wx * wy;
      float iou = inter / (aar + AR[j] - inter + 1e-9f);
      if (iou > 0.5f) bits |= (1ULL << bi);
    }
    ADJ[i * 10 + w] = bits;
  }
  __syncthreads();
  // phase 4: greedy suppression scan — wave 0, lane-parallel bitmask
  if (t < 64) {
    unsigned long long valid = 0, supp = 0;
    if (t < 10) {
      int jbase = t * 64;
      int jend = NANCH - jbase; if (jend > 64) jend = 64;
      for (int k = 0; k < jend; ++k)
        valid |= (unsigned long long)(SSc[jbase + k] > 0.3f ? 1 : 0) << k;
    }
    int cnt = 0;
    for (int w = 0; w < 10 && cnt < 100; ++w) {
      unsigned long long cur = shfl64(valid, w) & ~shfl64(supp, w);
      while (cur && cnt < 100) {
        int bpos = (int)__builtin_ctzll(cur);
        int i = w * 64 + bpos;
        if (t == 0) KEEP[cnt] = i;
        cnt++;
        unsigned long long a = (t < 10) ? ADJ[i * 10 + t] : 0ULL;
        if (t < w) a = 0ULL;
        else if (t == w) a &= ~((2ULL << bpos) - 1ULL);
        supp |= a;
        unsigned long long aw = shfl64(a, w);
        cur &= ~aw;
        cur &= ~(1ULL << bpos);
      }
    }
    if (t == 0) *CNT = cnt;
  }
  __syncthreads();
  // phase 5: write top-100 output
  int cnt = *CNT;
  if (t < 100) {
    float4 bx = make_float4(0.f, 0.f, 0.f, 0.f);
    float s = 0.f, vld = 0.f;
    if (t < cnt) {
      int i = KEEP[t];
      bx = SB4[i];
      s = SSc[i];
      vld = 1.f;
    }
    float* ob = out + (size_t)b * 600 + t * 6;
    ob[0] = bx.x; ob[1] = bx.y; ob[2] = bx.z; ob[3] = bx.w;
    ob[4] = s;    ob[5] = vld;
  }
}

// ---------------------------------------------------------------------------
extern "C" void kernel_launch(void* const* d_in, const int* in_sizes, int n_in,
                              void* d_out, int out_size, void* d_ws, size_t ws_size,
                              hipStream_t stream) {
  const float* feat = (const float*)d_in[0];
  const float* w1  = (const float*)d_in[1];
  const float* b1  = (const float*)d_in[2];
  const float* g1  = (const float*)d_in[3];
  const float* be1 = (const float*)d_in[4];
  const float* mu1 = (const float*)d_in[5];
  const float* v1  = (const float*)d_in[6];
  const float* w2  = (const float*)d_in[7];
  const float* b2  = (const float*)d_in[8];
  const float* g2  = (const float*)d_in[9];
  const float* be2 = (const float*)d_in[10];
  const float* mu2 = (const float*)d_in[11];
  const float* v2  = (const float*)d_in[12];
  const float* w3  = (const float*)d_in[13];
  const float* b3  = (const float*)d_in[14];
  const float* g3  = (const float*)d_in[15];
  const float* be3 = (const float*)d_in[16];
  const float* mu3 = (const float*)d_in[17];
  const float* v3  = (const float*)d_in[18];
  const float* w4  = (const float*)d_in[19];
  const float* b4  = (const float*)d_in[20];
  const float* g4  = (const float*)d_in[21];
  const float* be4 = (const float*)d_in[22];
  const float* mu4 = (const float*)d_in[23];
  const float* v4  = (const float*)d_in[24];
  const float* wcls = (const float*)d_in[25];
  const float* bcls = (const float*)d_in[26];
  const float* wbox = (const float*)d_in[27];
  const float* bbox = (const float*)d_in[28];

  const int B = in_sizes[0] / (512 * NPOS);
  float* ws  = (float*)d_ws;
  size_t xsz = (size_t)B * 256 * NPOS;
  float* xa  = ws;
  float* xb  = xa + xsz;
  float* w1t = xb + xsz;
  float* w2t = w1t + 131072;
  float* w3t = w2t + 589824;
  float* w4t = w3t + 589824;
  float* wbt = w4t + 589824;
  float* wct = wbt + 110592;
  float* BXg = wct + 27648;
  float* SCg = BXg + (size_t)B * (NANCH * 4);

  transpose_all<<<(2038784 + 255) / 256, 256, 0, stream>>>(
      w1, w2, w3, w4, wbox, wcls, w1t, w2t, w3t, w4t, wbt, wct);
  conv1x1_bn<<<B, 1024, 0, stream>>>(feat, w1t, b1, g1, be1, mu1, v1, xa);
  conv3x3_bn<<<B, 1024, 0, stream>>>(xa, w2t, b2, g2, be2, mu2, v2, xb);
  conv3x3_bn<<<B, 1024, 0, stream>>>(xb, w3t, b3, g3, be3, mu3, v3, xa);
  conv3x3_bn<<<B, 1024, 0, stream>>>(xa, w4t, b4, g4, be4, mu4, v4, xb);
  heads_decode<<<B, 512, 0, stream>>>(xb, wbt, wct, bbox, bcls, BXg, SCg);
  nms_kernel<<<B, 512, 0, stream>>>(BXg, SCg, (float*)d_out);
}

// Round 3
// 2239.626 us; speedup vs baseline: 1.0328x; 1.0328x over previous
//
#include <hip/hip_runtime.h>
#include <cmath>
#include <cstdint>

#define NPOS 49
#define NANCH 588

// ---------------------------------------------------------------------------
// Weight transposes.
// w1t[c*256+o] = w1[o*512+c]                  (1x1 conv, [c][o])
// wNt[ck*256+o] = wN[o*2304+ck]               (3x3 convs, [c*9+k][o])
// wbt[ck*48+o], wct[ck*12+o]                  (heads)
// ---------------------------------------------------------------------------
__global__ void transpose_all(
    const float* __restrict__ w1, const float* __restrict__ w2,
    const float* __restrict__ w3, const float* __restrict__ w4,
    const float* __restrict__ wb, const float* __restrict__ wc,
    float* __restrict__ w1t, float* __restrict__ w2t, float* __restrict__ w3t,
    float* __restrict__ w4t, float* __restrict__ wbt, float* __restrict__ wct) {
  int idx = blockIdx.x * blockDim.x + threadIdx.x;
  if (idx < 131072) { int o = idx / 512, c = idx % 512; w1t[c * 256 + o] = w1[idx]; return; }
  idx -= 131072;
  if (idx < 589824) { int o = idx / 2304, ck = idx % 2304; w2t[ck * 256 + o] = w2[idx]; return; }
  idx -= 589824;
  if (idx < 589824) { int o = idx / 2304, ck = idx % 2304; w3t[ck * 256 + o] = w3[idx]; return; }
  idx -= 589824;
  if (idx < 589824) { int o = idx / 2304, ck = idx % 2304; w4t[ck * 256 + o] = w4[idx]; return; }
  idx -= 589824;
  if (idx < 110592) { int o = idx / 2304, ck = idx % 2304; wbt[ck * 48 + o] = wb[idx]; return; }
  idx -= 110592;
  if (idx < 27648)  { int o = idx / 2304, ck = idx % 2304; wct[ck * 12 + o] = wc[idx]; return; }
}

// ---------------------------------------------------------------------------
// conv 1x1 (512 -> 256) + bias + BN + ReLU.
// Grid = 2*B: block = (image, o-half of 128).  512 thr = 128 o x 4-way K-split.
// LDS: two phases of 256 input channels, [256][52] = 53.2 KB -> 2 blocks/CU.
// ---------------------------------------------------------------------------
__global__ __launch_bounds__(512, 4) void conv1x1_bn(
    const float* __restrict__ in, const float* __restrict__ wt,
    const float* __restrict__ bias, const float* __restrict__ gg,
    const float* __restrict__ be, const float* __restrict__ mu,
    const float* __restrict__ var, float* __restrict__ out) {
  __shared__ float smem[256 * 52];
  const int blk = blockIdx.x, t = threadIdx.x;
  const int b = blk >> 1, oh = blk & 1;
  const int o = t & 127, cg = t >> 7;      // cg in 0..3
  const int og = oh * 128 + o;
  const float* inb = in + (size_t)b * (512 * NPOS);
  float acc[NPOS];
#pragma unroll
  for (int p = 0; p < NPOS; ++p) acc[p] = 0.f;
  for (int h = 0; h < 2; ++h) {
    __syncthreads();
    for (int i = t; i < 256 * NPOS; i += 512) {
      int c = i / NPOS, p = i - c * NPOS;
      smem[c * 52 + p] = inb[(h * 256 + c) * NPOS + p];
    }
    __syncthreads();
    const int c0 = cg * 64;
    for (int cl = c0; cl < c0 + 64; ++cl) {
      float wv = wt[(h * 256 + cl) * 256 + og];
      const float4* tr = (const float4*)(smem + cl * 52);
#pragma unroll
      for (int j = 0; j < 12; ++j) {
        float4 q = tr[j];
        acc[4 * j + 0] = fmaf(wv, q.x, acc[4 * j + 0]);
        acc[4 * j + 1] = fmaf(wv, q.y, acc[4 * j + 1]);
        acc[4 * j + 2] = fmaf(wv, q.z, acc[4 * j + 2]);
        acc[4 * j + 3] = fmaf(wv, q.w, acc[4 * j + 3]);
      }
      acc[48] = fmaf(wv, smem[cl * 52 + 48], acc[48]);
    }
  }
  __syncthreads();
  float* P0 = smem;
  float* P1 = smem + 6272;
  if (cg == 1) { for (int p = 0; p < NPOS; ++p) P0[o * NPOS + p] = acc[p]; }
  if (cg == 3) { for (int p = 0; p < NPOS; ++p) P1[o * NPOS + p] = acc[p]; }
  __syncthreads();
  if (cg == 0) { for (int p = 0; p < NPOS; ++p) acc[p] += P0[o * NPOS + p]; }
  if (cg == 2) { for (int p = 0; p < NPOS; ++p) acc[p] += P1[o * NPOS + p]; }
  __syncthreads();
  if (cg == 2) { for (int p = 0; p < NPOS; ++p) P0[o * NPOS + p] = acc[p]; }
  __syncthreads();
  if (cg == 0) {
    float scale = gg[og] / sqrtf(var[og] + 1e-5f);
    float add = (bias[og] - mu[og]) * scale + be[og];
#pragma unroll
    for (int p = 0; p < NPOS; ++p) {
      float v = (acc[p] + P0[o * NPOS + p]) * scale + add;
      P1[o * NPOS + p] = v > 0.f ? v : 0.f;
    }
  }
  __syncthreads();
  float* outb = out + (size_t)b * (256 * NPOS) + oh * (128 * NPOS);
  for (int i = t; i < 128 * NPOS; i += 512) outb[i] = P1[i];
}

// ---------------------------------------------------------------------------
// conv 3x3 pad1 (256 -> 256) + bias + BN + ReLU.
// Grid = 2*B: block = (image, o-half of 128).  512 thr = 128 o x 4-way K-split.
// LDS: two phases of 128 input channels, [128][9][12] = 55.3 KB -> 2 blocks/CU.
// ---------------------------------------------------------------------------
#define LOADROW(dst, base, rr)                                          \
  do {                                                                  \
    const float4* q4_ = (const float4*)((base) + (rr) * 12);            \
    float4 q0_ = q4_[0], q1_ = q4_[1], q2_ = q4_[2];                    \
    dst[0] = q0_.x; dst[1] = q0_.y; dst[2] = q0_.z; dst[3] = q0_.w;     \
    dst[4] = q1_.x; dst[5] = q1_.y; dst[6] = q1_.z; dst[7] = q1_.w;     \
    dst[8] = q2_.x;                                                     \
  } while (0)

__global__ __launch_bounds__(512, 4) void conv3x3_bn(
    const float* __restrict__ in, const float* __restrict__ wt,
    const float* __restrict__ bias, const float* __restrict__ gg,
    const float* __restrict__ be, const float* __restrict__ mu,
    const float* __restrict__ var, float* __restrict__ out) {
  __shared__ float smem[128 * 108];  // 55,296 B
  const int blk = blockIdx.x, t = threadIdx.x;
  const int b = blk >> 1, oh = blk & 1;
  const int o = t & 127, cg = t >> 7;      // cg in 0..3
  const int og = oh * 128 + o;
  const float* inb = in + (size_t)b * (256 * NPOS);
  for (int i = t; i < 128 * 108; i += 512) smem[i] = 0.f;  // borders stay 0
  float acc[NPOS];
#pragma unroll
  for (int p = 0; p < NPOS; ++p) acc[p] = 0.f;
  for (int h = 0; h < 2; ++h) {
    __syncthreads();  // zero done / previous compute done (WAR)
    for (int i = t; i < 128 * NPOS; i += 512) {
      int c = i / NPOS, p = i - c * NPOS, y = p / 7, x = p - y * 7;
      smem[c * 108 + (y + 1) * 12 + (x + 1)] = inb[(h * 128 + c) * NPOS + p];
    }
    __syncthreads();
    const int c0 = cg * 32;
    for (int cl = c0; cl < c0 + 32; ++cl) {
      const int c = h * 128 + cl;
      float w[9];
#pragma unroll
      for (int k = 0; k < 9; ++k) w[k] = wt[(c * 9 + k) * 256 + og];
      const float* tb = smem + cl * 108;
      float R[3][9];
      LOADROW(R[0], tb, 0);
      LOADROW(R[1], tb, 1);
#pragma unroll
      for (int y = 0; y < 7; ++y) {
        LOADROW(R[(y + 2) % 3], tb, y + 2);
        const float* r0 = R[y % 3];
        const float* r1 = R[(y + 1) % 3];
        const float* r2 = R[(y + 2) % 3];
#pragma unroll
        for (int x = 0; x < 7; ++x) {
          float s = acc[y * 7 + x];
          s = fmaf(w[0], r0[x], s);
          s = fmaf(w[1], r0[x + 1], s);
          s = fmaf(w[2], r0[x + 2], s);
          s = fmaf(w[3], r1[x], s);
          s = fmaf(w[4], r1[x + 1], s);
          s = fmaf(w[5], r1[x + 2], s);
          s = fmaf(w[6], r2[x], s);
          s = fmaf(w[7], r2[x + 1], s);
          s = fmaf(w[8], r2[x + 2], s);
          acc[y * 7 + x] = s;
        }
      }
    }
  }
  __syncthreads();
  float* P0 = smem;
  float* P1 = smem + 6272;
  if (cg == 1) { for (int p = 0; p < NPOS; ++p) P0[o * NPOS + p] = acc[p]; }
  if (cg == 3) { for (int p = 0; p < NPOS; ++p) P1[o * NPOS + p] = acc[p]; }
  __syncthreads();
  if (cg == 0) { for (int p = 0; p < NPOS; ++p) acc[p] += P0[o * NPOS + p]; }
  if (cg == 2) { for (int p = 0; p < NPOS; ++p) acc[p] += P1[o * NPOS + p]; }
  __syncthreads();
  if (cg == 2) { for (int p = 0; p < NPOS; ++p) P0[o * NPOS + p] = acc[p]; }
  __syncthreads();
  if (cg == 0) {
    float scale = gg[og] / sqrtf(var[og] + 1e-5f);
    float add = (bias[og] - mu[og]) * scale + be[og];
#pragma unroll
    for (int p = 0; p < NPOS; ++p) {
      float v = (acc[p] + P0[o * NPOS + p]) * scale + add;
      P1[o * NPOS + p] = v > 0.f ? v : 0.f;
    }
  }
  __syncthreads();
  float* outb = out + (size_t)b * (256 * NPOS) + oh * (128 * NPOS);
  for (int i = t; i < 128 * NPOS; i += 512) outb[i] = P1[i];
}

// ---------------------------------------------------------------------------
// Heads (box 48ch + cls 12ch, 3x3 pad1) + decode + sigmoid.
// 512 threads: 60 out-ch x 8-way K-split.  Writes BX[588*4], SC[588] per img.
// ---------------------------------------------------------------------------
__global__ __launch_bounds__(512, 2) void heads_decode(
    const float* __restrict__ in, const float* __restrict__ wbt,
    const float* __restrict__ wct, const float* __restrict__ bb,
    const float* __restrict__ bc, float* __restrict__ BXg,
    float* __restrict__ SCg) {
  __shared__ float smem[256 * 108];
  const int b = blockIdx.x, t = threadIdx.x;
  for (int i = t; i < 256 * 108; i += 512) smem[i] = 0.f;
  __syncthreads();
  const float* inb = in + (size_t)b * (256 * NPOS);
  for (int i = t; i < 256 * NPOS; i += 512) {
    int c = i / NPOS, p = i - c * NPOS, y = p / 7, x = p - y * 7;
    smem[c * 108 + (y + 1) * 12 + (x + 1)] = inb[i];
  }
  __syncthreads();
  float acc[NPOS];
#pragma unroll
  for (int p = 0; p < NPOS; ++p) acc[p] = 0.f;
  int o = 0, cg = 0;
  if (t < 480) {
    o = t % 60; cg = t / 60;  // 8-way K-split, 32 c each
    const float* wbase; int wstr;
    if (o < 48) { wbase = wbt + o; wstr = 48; }
    else        { wbase = wct + (o - 48); wstr = 12; }
    const int c0 = cg * 32;
    for (int c = c0; c < c0 + 32; ++c) {
      float w[9];
#pragma unroll
      for (int k = 0; k < 9; ++k) w[k] = wbase[(c * 9 + k) * wstr];
      const float* tb = smem + c * 108;
      float R[3][9];
      LOADROW(R[0], tb, 0);
      LOADROW(R[1], tb, 1);
#pragma unroll
      for (int y = 0; y < 7; ++y) {
        LOADROW(R[(y + 2) % 3], tb, y + 2);
        const float* r0 = R[y % 3];
        const float* r1 = R[(y + 1) % 3];
        const float* r2 = R[(y + 2) % 3];
#pragma unroll
        for (int x = 0; x < 7; ++x) {
          float s = acc[y * 7 + x];
          s = fmaf(w[0], r0[x], s);
          s = fmaf(w[1], r0[x + 1], s);
          s = fmaf(w[2], r0[x + 2], s);
          s = fmaf(w[3], r1[x], s);
          s = fmaf(w[4], r1[x + 1], s);
          s = fmaf(w[5], r1[x + 2], s);
          s = fmaf(w[6], r2[x], s);
          s = fmaf(w[7], r2[x + 1], s);
          s = fmaf(w[8], r2[x + 2], s);
          acc[y * 7 + x] = s;
        }
      }
    }
  }
  __syncthreads();
  float* part = smem;            // [7][60][49]
  float* H = smem + 7 * 2940;    // [60][49]
  if (t < 480 && cg > 0) {
#pragma unroll
    for (int p = 0; p < NPOS; ++p) part[(cg - 1) * 2940 + o * NPOS + p] = acc[p];
  }
  __syncthreads();
  if (t < 60) {  // cg == 0
    float bsum = (o < 48) ? bb[o] : bc[o - 48];
#pragma unroll
    for (int p = 0; p < NPOS; ++p) {
      float v = acc[p] + bsum;
      for (int g = 0; g < 7; ++g) v += part[g * 2940 + o * NPOS + p];
      H[o * NPOS + p] = v;
    }
  }
  __syncthreads();
  const float scl[4] = {0.3f, 0.5f, 0.7f, 0.9f};
  const float rat[3] = {0.7f, 1.0f, 1.3f};
  for (int n = t; n < NANCH; n += 512) {
    int p = n / 12, a = n - p * 12;
    int ph = p / 7, pw = p - ph * 7;
    float cx = (ph + 0.5f) / 7.0f;
    float cy = (pw + 0.5f) / 7.0f;
    int s = a / 3, r = a - s * 3;
    float rt = sqrtf(rat[r]);
    float wsz = scl[s] * rt, hsz = scl[s] / rt;
    float x1 = cx + (-wsz) * 0.5f, y1 = cy + (-hsz) * 0.5f;
    float x2 = cx + wsz * 0.5f,    y2 = cy + hsz * 0.5f;
    float acx = (x1 + x2) * 0.5f,  acy = (y1 + y2) * 0.5f;
    float asx = x2 - x1,           asy = y2 - y1;
    float bp0 = H[(a * 4 + 0) * NPOS + p];
    float bp1 = H[(a * 4 + 1) * NPOS + p];
    float bp2 = H[(a * 4 + 2) * NPOS + p];
    float bp3 = H[(a * 4 + 3) * NPOS + p];
    float pcx = bp0 * asx + acx;
    float pcy = bp1 * asy + acy;
    float psx = expf(bp2) * asx;
    float psy = expf(bp3) * asy;
    float* bx = BXg + (size_t)b * (NANCH * 4) + n * 4;
    bx[0] = pcx - psx * 0.5f;
    bx[1] = pcy - psy * 0.5f;
    bx[2] = pcx + psx * 0.5f;
    bx[3] = pcy + psy * 0.5f;
    float lg = H[(48 + a) * NPOS + p];
    SCg[(size_t)b * NANCH + n] = 1.0f / (1.0f + expf(-lg));
  }
}

// ---------------------------------------------------------------------------
// NMS: rank sort + IoU bitmask + wave-parallel greedy scan.  512 thr, 66 KB.
// ---------------------------------------------------------------------------
__device__ inline unsigned long long shfl64(unsigned long long v, int lane) {
  int lo = __shfl((int)(unsigned)(v & 0xffffffffULL), lane, 64);
  int hi = __shfl((int)(unsigned)(v >> 32), lane, 64);
  return ((unsigned long long)(unsigned)hi << 32) | (unsigned)lo;
}

__global__ __launch_bounds__(512, 4) void nms_kernel(
    const float* __restrict__ BXg, const float* __restrict__ SCg,
    float* __restrict__ out) {
  __shared__ float smem[16576];
  unsigned long long* KEY = (unsigned long long*)smem;          // [588]
  float* SB  = smem + 1176;                                     // [588*4]
  float* SSc = smem + 3528;                                     // [588]
  float* AR  = smem + 4116;                                     // [588]
  unsigned long long* ADJ = (unsigned long long*)(smem + 4704); // [588*10]
  int* KEEP = (int*)(smem + 16464);                             // [100]
  int* CNT  = (int*)(smem + 16564);
  const int b = blockIdx.x, t = threadIdx.x;
  const float* scb = SCg + (size_t)b * NANCH;
  const float4* bxb = (const float4*)(BXg + (size_t)b * (NANCH * 4));
  for (int i = t; i < NANCH; i += 512) {
    unsigned u = __float_as_uint(scb[i]);
    u = (u & 0x80000000u) ? ~u : (u | 0x80000000u);
    u = ~u;
    KEY[i] = ((unsigned long long)u << 32) | (unsigned)i;
  }
  __syncthreads();
  for (int i = t; i < NANCH; i += 512) {
    unsigned long long k = KEY[i];
    int rank = 0;
    for (int j = 0; j < NANCH; ++j) rank += (KEY[j] < k) ? 1 : 0;
    float4 bx = bxb[i];
    ((float4*)SB)[rank] = bx;
    SSc[rank] = scb[i];
    AR[rank] = (bx.z - bx.x) * (bx.w - bx.y);
  }
  __syncthreads();
  const float4* SB4 = (const float4*)SB;
  for (int task = t; task < NANCH * 10; task += 512) {
    int i = task % NANCH, w = task / NANCH;
    float4 a = SB4[i];
    float aar = AR[i];
    int jbase = w * 64;
    int jend = NANCH - jbase; if (jend > 64) jend = 64;
    unsigned long long bits = 0;
    for (int bi = 0; bi < jend; ++bi) {
      int j = jbase + bi;
      float4 bb = SB4[j];
      float ltx = fmaxf(a.x, bb.x), lty = fmaxf(a.y, bb.y);
      float rbx = fminf(a.z, bb.z), rby = fminf(a.w, bb.w);
      float wx = rbx - ltx; wx = wx > 0.f ? wx : 0.f;
      float wy = rby - lty; wy = wy > 0.f ? wy : 0.f;
      float inter = wx * wy;
      float iou = inter / (aar + AR[j] - inter + 1e-9f);
      if (iou > 0.5f) bits |= (1ULL << bi);
    }
    ADJ[i * 10 + w] = bits;
  }
  __syncthreads();
  if (t < 64) {
    unsigned long long valid = 0, supp = 0;
    if (t < 10) {
      int jbase = t * 64;
      int jend = NANCH - jbase; if (jend > 64) jend = 64;
      for (int k = 0; k < jend; ++k)
        valid |= (unsigned long long)(SSc[jbase + k] > 0.3f ? 1 : 0) << k;
    }
    int cnt = 0;
    for (int w = 0; w < 10 && cnt < 100; ++w) {
      unsigned long long cur = shfl64(valid, w) & ~shfl64(supp, w);
      while (cur && cnt < 100) {
        int bpos = (int)__builtin_ctzll(cur);
        int i = w * 64 + bpos;
        if (t == 0) KEEP[cnt] = i;
        cnt++;
        unsigned long long a = (t < 10) ? ADJ[i * 10 + t] : 0ULL;
        if (t < w) a = 0ULL;
        else if (t == w) a &= ~((2ULL << bpos) - 1ULL);
        supp |= a;
        unsigned long long aw = shfl64(a, w);
        cur &= ~aw;
        cur &= ~(1ULL << bpos);
      }
    }
    if (t == 0) *CNT = cnt;
  }
  __syncthreads();
  int cnt = *CNT;
  if (t < 100) {
    float4 bx = make_float4(0.f, 0.f, 0.f, 0.f);
    float s = 0.f, vld = 0.f;
    if (t < cnt) {
      int i = KEEP[t];
      bx = SB4[i];
      s = SSc[i];
      vld = 1.f;
    }
    float* ob = out + (size_t)b * 600 + t * 6;
    ob[0] = bx.x; ob[1] = bx.y; ob[2] = bx.z; ob[3] = bx.w;
    ob[4] = s;    ob[5] = vld;
  }
}

// ---------------------------------------------------------------------------
extern "C" void kernel_launch(void* const* d_in, const int* in_sizes, int n_in,
                              void* d_out, int out_size, void* d_ws, size_t ws_size,
                              hipStream_t stream) {
  const float* feat = (const float*)d_in[0];
  const float* w1  = (const float*)d_in[1];
  const float* b1  = (const float*)d_in[2];
  const float* g1  = (const float*)d_in[3];
  const float* be1 = (const float*)d_in[4];
  const float* mu1 = (const float*)d_in[5];
  const float* v1  = (const float*)d_in[6];
  const float* w2  = (const float*)d_in[7];
  const float* b2  = (const float*)d_in[8];
  const float* g2  = (const float*)d_in[9];
  const float* be2 = (const float*)d_in[10];
  const float* mu2 = (const float*)d_in[11];
  const float* v2  = (const float*)d_in[12];
  const float* w3  = (const float*)d_in[13];
  const float* b3  = (const float*)d_in[14];
  const float* g3  = (const float*)d_in[15];
  const float* be3 = (const float*)d_in[16];
  const float* mu3 = (const float*)d_in[17];
  const float* v3  = (const float*)d_in[18];
  const float* w4  = (const float*)d_in[19];
  const float* b4  = (const float*)d_in[20];
  const float* g4  = (const float*)d_in[21];
  const float* be4 = (const float*)d_in[22];
  const float* mu4 = (const float*)d_in[23];
  const float* v4  = (const float*)d_in[24];
  const float* wcls = (const float*)d_in[25];
  const float* bcls = (const float*)d_in[26];
  const float* wbox = (const float*)d_in[27];
  const float* bbox = (const float*)d_in[28];

  const int B = in_sizes[0] / (512 * NPOS);
  float* ws  = (float*)d_ws;
  size_t xsz = (size_t)B * 256 * NPOS;
  float* xa  = ws;
  float* xb  = xa + xsz;
  float* w1t = xb + xsz;
  float* w2t = w1t + 131072;
  float* w3t = w2t + 589824;
  float* w4t = w3t + 589824;
  float* wbt = w4t + 589824;
  float* wct = wbt + 110592;
  float* BXg = wct + 27648;
  float* SCg = BXg + (size_t)B * (NANCH * 4);

  transpose_all<<<(2038784 + 255) / 256, 256, 0, stream>>>(
      w1, w2, w3, w4, wbox, wcls, w1t, w2t, w3t, w4t, wbt, wct);
  conv1x1_bn<<<2 * B, 512, 0, stream>>>(feat, w1t, b1, g1, be1, mu1, v1, xa);
  conv3x3_bn<<<2 * B, 512, 0, stream>>>(xa, w2t, b2, g2, be2, mu2, v2, xb);
  conv3x3_bn<<<2 * B, 512, 0, stream>>>(xb, w3t, b3, g3, be3, mu3, v3, xa);
  conv3x3_bn<<<2 * B, 512, 0, stream>>>(xa, w4t, b4, g4, be4, mu4, v4, xb);
  heads_decode<<<B, 512, 0, stream>>>(xb, wbt, wct, bbox, bcls, BXg, SCg);
  nms_kernel<<<B, 512, 0, stream>>>(BXg, SCg, (float*)d_out);
}

// Round 4
// 994.606 us; speedup vs baseline: 2.3256x; 2.2518x over previous
//
#include <hip/hip_runtime.h>
#include <cmath>
#include <cstdint>

#define NPOS 49
#define NANCH 588

// ---------------------------------------------------------------------------
// Weight transposes.
// w1t[c*256+o] = w1[o*512+c]                  (1x1 conv, [c][o])
// wNt[ck*256+o] = wN[o*2304+ck]               (3x3 convs, [c*9+k][o])
// wbt[ck*48+o], wct[ck*12+o]                  (heads)
// ---------------------------------------------------------------------------
__global__ void transpose_all(
    const float* __restrict__ w1, const float* __restrict__ w2,
    const float* __restrict__ w3, const float* __restrict__ w4,
    const float* __restrict__ wb, const float* __restrict__ wc,
    float* __restrict__ w1t, float* __restrict__ w2t, float* __restrict__ w3t,
    float* __restrict__ w4t, float* __restrict__ wbt, float* __restrict__ wct) {
  int idx = blockIdx.x * blockDim.x + threadIdx.x;
  if (idx < 131072) { int o = idx / 512, c = idx % 512; w1t[c * 256 + o] = w1[idx]; return; }
  idx -= 131072;
  if (idx < 589824) { int o = idx / 2304, ck = idx % 2304; w2t[ck * 256 + o] = w2[idx]; return; }
  idx -= 589824;
  if (idx < 589824) { int o = idx / 2304, ck = idx % 2304; w3t[ck * 256 + o] = w3[idx]; return; }
  idx -= 589824;
  if (idx < 589824) { int o = idx / 2304, ck = idx % 2304; w4t[ck * 256 + o] = w4[idx]; return; }
  idx -= 589824;
  if (idx < 110592) { int o = idx / 2304, ck = idx % 2304; wbt[ck * 48 + o] = wb[idx]; return; }
  idx -= 110592;
  if (idx < 27648)  { int o = idx / 2304, ck = idx % 2304; wct[ck * 12 + o] = wc[idx]; return; }
}

// ---------------------------------------------------------------------------
// conv 1x1 (512 -> 256) + bias + BN + ReLU.
// Grid = 2*B: block = (image, o-half of 128).  512 thr = 128 o x 4-way K-split.
// LDS: two phases of 256 input channels, [256][52] = 53.2 KB -> 2 blocks/CU.
// __launch_bounds__(512,2): 2 blocks/CU (CUDA-style semantics) -> VGPR cap 128,
// no spill (cap 64 at min-blocks=4 spilled acc[] to scratch in rounds 2-3).
// ---------------------------------------------------------------------------
__global__ __launch_bounds__(512, 2) void conv1x1_bn(
    const float* __restrict__ in, const float* __restrict__ wt,
    const float* __restrict__ bias, const float* __restrict__ gg,
    const float* __restrict__ be, const float* __restrict__ mu,
    const float* __restrict__ var, float* __restrict__ out) {
  __shared__ float smem[256 * 52];
  const int blk = blockIdx.x, t = threadIdx.x;
  const int b = blk >> 1, oh = blk & 1;
  const int o = t & 127, cg = t >> 7;      // cg in 0..3
  const int og = oh * 128 + o;
  const float* inb = in + (size_t)b * (512 * NPOS);
  float acc[NPOS];
#pragma unroll
  for (int p = 0; p < NPOS; ++p) acc[p] = 0.f;
  for (int h = 0; h < 2; ++h) {
    __syncthreads();
    for (int i = t; i < 256 * NPOS; i += 512) {
      int c = i / NPOS, p = i - c * NPOS;
      smem[c * 52 + p] = inb[(h * 256 + c) * NPOS + p];
    }
    __syncthreads();
    const int c0 = cg * 64;
    for (int cl = c0; cl < c0 + 64; ++cl) {
      float wv = wt[(h * 256 + cl) * 256 + og];
      const float4* tr = (const float4*)(smem + cl * 52);
#pragma unroll
      for (int j = 0; j < 12; ++j) {
        float4 q = tr[j];
        acc[4 * j + 0] = fmaf(wv, q.x, acc[4 * j + 0]);
        acc[4 * j + 1] = fmaf(wv, q.y, acc[4 * j + 1]);
        acc[4 * j + 2] = fmaf(wv, q.z, acc[4 * j + 2]);
        acc[4 * j + 3] = fmaf(wv, q.w, acc[4 * j + 3]);
      }
      acc[48] = fmaf(wv, smem[cl * 52 + 48], acc[48]);
    }
  }
  __syncthreads();
  float* P0 = smem;
  float* P1 = smem + 6272;
  if (cg == 1) { for (int p = 0; p < NPOS; ++p) P0[o * NPOS + p] = acc[p]; }
  if (cg == 3) { for (int p = 0; p < NPOS; ++p) P1[o * NPOS + p] = acc[p]; }
  __syncthreads();
  if (cg == 0) { for (int p = 0; p < NPOS; ++p) acc[p] += P0[o * NPOS + p]; }
  if (cg == 2) { for (int p = 0; p < NPOS; ++p) acc[p] += P1[o * NPOS + p]; }
  __syncthreads();
  if (cg == 2) { for (int p = 0; p < NPOS; ++p) P0[o * NPOS + p] = acc[p]; }
  __syncthreads();
  if (cg == 0) {
    float scale = gg[og] / sqrtf(var[og] + 1e-5f);
    float add = (bias[og] - mu[og]) * scale + be[og];
#pragma unroll
    for (int p = 0; p < NPOS; ++p) {
      float v = (acc[p] + P0[o * NPOS + p]) * scale + add;
      P1[o * NPOS + p] = v > 0.f ? v : 0.f;
    }
  }
  __syncthreads();
  float* outb = out + (size_t)b * (256 * NPOS) + oh * (128 * NPOS);
  for (int i = t; i < 128 * NPOS; i += 512) outb[i] = P1[i];
}

// ---------------------------------------------------------------------------
// conv 3x3 pad1 (256 -> 256) + bias + BN + ReLU.
// Grid = 2*B: block = (image, o-half of 128).  512 thr = 128 o x 4-way K-split.
// LDS: two phases of 128 input channels, [128][9][12] = 55.3 KB -> 2 blocks/CU.
// ---------------------------------------------------------------------------
#define LOADROW(dst, base, rr)                                          \
  do {                                                                  \
    const float4* q4_ = (const float4*)((base) + (rr) * 12);            \
    float4 q0_ = q4_[0], q1_ = q4_[1], q2_ = q4_[2];                    \
    dst[0] = q0_.x; dst[1] = q0_.y; dst[2] = q0_.z; dst[3] = q0_.w;     \
    dst[4] = q1_.x; dst[5] = q1_.y; dst[6] = q1_.z; dst[7] = q1_.w;     \
    dst[8] = q2_.x;                                                     \
  } while (0)

__global__ __launch_bounds__(512, 2) void conv3x3_bn(
    const float* __restrict__ in, const float* __restrict__ wt,
    const float* __restrict__ bias, const float* __restrict__ gg,
    const float* __restrict__ be, const float* __restrict__ mu,
    const float* __restrict__ var, float* __restrict__ out) {
  __shared__ float smem[128 * 108];  // 55,296 B
  const int blk = blockIdx.x, t = threadIdx.x;
  const int b = blk >> 1, oh = blk & 1;
  const int o = t & 127, cg = t >> 7;      // cg in 0..3
  const int og = oh * 128 + o;
  const float* inb = in + (size_t)b * (256 * NPOS);
  for (int i = t; i < 128 * 108; i += 512) smem[i] = 0.f;  // borders stay 0
  float acc[NPOS];
#pragma unroll
  for (int p = 0; p < NPOS; ++p) acc[p] = 0.f;
  for (int h = 0; h < 2; ++h) {
    __syncthreads();  // zero done / previous compute done (WAR)
    for (int i = t; i < 128 * NPOS; i += 512) {
      int c = i / NPOS, p = i - c * NPOS, y = p / 7, x = p - y * 7;
      smem[c * 108 + (y + 1) * 12 + (x + 1)] = inb[(h * 128 + c) * NPOS + p];
    }
    __syncthreads();
    const int c0 = cg * 32;
    for (int cl = c0; cl < c0 + 32; ++cl) {
      const int c = h * 128 + cl;
      float w[9];
#pragma unroll
      for (int k = 0; k < 9; ++k) w[k] = wt[(c * 9 + k) * 256 + og];
      const float* tb = smem + cl * 108;
      float R[3][9];
      LOADROW(R[0], tb, 0);
      LOADROW(R[1], tb, 1);
#pragma unroll
      for (int y = 0; y < 7; ++y) {
        LOADROW(R[(y + 2) % 3], tb, y + 2);
        const float* r0 = R[y % 3];
        const float* r1 = R[(y + 1) % 3];
        const float* r2 = R[(y + 2) % 3];
#pragma unroll
        for (int x = 0; x < 7; ++x) {
          float s = acc[y * 7 + x];
          s = fmaf(w[0], r0[x], s);
          s = fmaf(w[1], r0[x + 1], s);
          s = fmaf(w[2], r0[x + 2], s);
          s = fmaf(w[3], r1[x], s);
          s = fmaf(w[4], r1[x + 1], s);
          s = fmaf(w[5], r1[x + 2], s);
          s = fmaf(w[6], r2[x], s);
          s = fmaf(w[7], r2[x + 1], s);
          s = fmaf(w[8], r2[x + 2], s);
          acc[y * 7 + x] = s;
        }
      }
    }
  }
  __syncthreads();
  float* P0 = smem;
  float* P1 = smem + 6272;
  if (cg == 1) { for (int p = 0; p < NPOS; ++p) P0[o * NPOS + p] = acc[p]; }
  if (cg == 3) { for (int p = 0; p < NPOS; ++p) P1[o * NPOS + p] = acc[p]; }
  __syncthreads();
  if (cg == 0) { for (int p = 0; p < NPOS; ++p) acc[p] += P0[o * NPOS + p]; }
  if (cg == 2) { for (int p = 0; p < NPOS; ++p) acc[p] += P1[o * NPOS + p]; }
  __syncthreads();
  if (cg == 2) { for (int p = 0; p < NPOS; ++p) P0[o * NPOS + p] = acc[p]; }
  __syncthreads();
  if (cg == 0) {
    float scale = gg[og] / sqrtf(var[og] + 1e-5f);
    float add = (bias[og] - mu[og]) * scale + be[og];
#pragma unroll
    for (int p = 0; p < NPOS; ++p) {
      float v = (acc[p] + P0[o * NPOS + p]) * scale + add;
      P1[o * NPOS + p] = v > 0.f ? v : 0.f;
    }
  }
  __syncthreads();
  float* outb = out + (size_t)b * (256 * NPOS) + oh * (128 * NPOS);
  for (int i = t; i < 128 * NPOS; i += 512) outb[i] = P1[i];
}

// ---------------------------------------------------------------------------
// Heads (box 48ch + cls 12ch, 3x3 pad1) + decode + sigmoid.
// 512 threads: 60 out-ch x 8-way K-split.  Writes BX[588*4], SC[588] per img.
// ---------------------------------------------------------------------------
__global__ __launch_bounds__(512, 2) void heads_decode(
    const float* __restrict__ in, const float* __restrict__ wbt,
    const float* __restrict__ wct, const float* __restrict__ bb,
    const float* __restrict__ bc, float* __restrict__ BXg,
    float* __restrict__ SCg) {
  __shared__ float smem[256 * 108];
  const int b = blockIdx.x, t = threadIdx.x;
  for (int i = t; i < 256 * 108; i += 512) smem[i] = 0.f;
  __syncthreads();
  const float* inb = in + (size_t)b * (256 * NPOS);
  for (int i = t; i < 256 * NPOS; i += 512) {
    int c = i / NPOS, p = i - c * NPOS, y = p / 7, x = p - y * 7;
    smem[c * 108 + (y + 1) * 12 + (x + 1)] = inb[i];
  }
  __syncthreads();
  float acc[NPOS];
#pragma unroll
  for (int p = 0; p < NPOS; ++p) acc[p] = 0.f;
  int o = 0, cg = 0;
  if (t < 480) {
    o = t % 60; cg = t / 60;  // 8-way K-split, 32 c each
    const float* wbase; int wstr;
    if (o < 48) { wbase = wbt + o; wstr = 48; }
    else        { wbase = wct + (o - 48); wstr = 12; }
    const int c0 = cg * 32;
    for (int c = c0; c < c0 + 32; ++c) {
      float w[9];
#pragma unroll
      for (int k = 0; k < 9; ++k) w[k] = wbase[(c * 9 + k) * wstr];
      const float* tb = smem + c * 108;
      float R[3][9];
      LOADROW(R[0], tb, 0);
      LOADROW(R[1], tb, 1);
#pragma unroll
      for (int y = 0; y < 7; ++y) {
        LOADROW(R[(y + 2) % 3], tb, y + 2);
        const float* r0 = R[y % 3];
        const float* r1 = R[(y + 1) % 3];
        const float* r2 = R[(y + 2) % 3];
#pragma unroll
        for (int x = 0; x < 7; ++x) {
          float s = acc[y * 7 + x];
          s = fmaf(w[0], r0[x], s);
          s = fmaf(w[1], r0[x + 1], s);
          s = fmaf(w[2], r0[x + 2], s);
          s = fmaf(w[3], r1[x], s);
          s = fmaf(w[4], r1[x + 1], s);
          s = fmaf(w[5], r1[x + 2], s);
          s = fmaf(w[6], r2[x], s);
          s = fmaf(w[7], r2[x + 1], s);
          s = fmaf(w[8], r2[x + 2], s);
          acc[y * 7 + x] = s;
        }
      }
    }
  }
  __syncthreads();
  float* part = smem;            // [7][60][49]
  float* H = smem + 7 * 2940;    // [60][49]
  if (t < 480 && cg > 0) {
#pragma unroll
    for (int p = 0; p < NPOS; ++p) part[(cg - 1) * 2940 + o * NPOS + p] = acc[p];
  }
  __syncthreads();
  if (t < 60) {  // cg == 0
    float bsum = (o < 48) ? bb[o] : bc[o - 48];
#pragma unroll
    for (int p = 0; p < NPOS; ++p) {
      float v = acc[p] + bsum;
      for (int g = 0; g < 7; ++g) v += part[g * 2940 + o * NPOS + p];
      H[o * NPOS + p] = v;
    }
  }
  __syncthreads();
  const float scl[4] = {0.3f, 0.5f, 0.7f, 0.9f};
  const float rat[3] = {0.7f, 1.0f, 1.3f};
  for (int n = t; n < NANCH; n += 512) {
    int p = n / 12, a = n - p * 12;
    int ph = p / 7, pw = p - ph * 7;
    float cx = (ph + 0.5f) / 7.0f;
    float cy = (pw + 0.5f) / 7.0f;
    int s = a / 3, r = a - s * 3;
    float rt = sqrtf(rat[r]);
    float wsz = scl[s] * rt, hsz = scl[s] / rt;
    float x1 = cx + (-wsz) * 0.5f, y1 = cy + (-hsz) * 0.5f;
    float x2 = cx + wsz * 0.5f,    y2 = cy + hsz * 0.5f;
    float acx = (x1 + x2) * 0.5f,  acy = (y1 + y2) * 0.5f;
    float asx = x2 - x1,           asy = y2 - y1;
    float bp0 = H[(a * 4 + 0) * NPOS + p];
    float bp1 = H[(a * 4 + 1) * NPOS + p];
    float bp2 = H[(a * 4 + 2) * NPOS + p];
    float bp3 = H[(a * 4 + 3) * NPOS + p];
    float pcx = bp0 * asx + acx;
    float pcy = bp1 * asy + acy;
    float psx = expf(bp2) * asx;
    float psy = expf(bp3) * asy;
    float* bx = BXg + (size_t)b * (NANCH * 4) + n * 4;
    bx[0] = pcx - psx * 0.5f;
    bx[1] = pcy - psy * 0.5f;
    bx[2] = pcx + psx * 0.5f;
    bx[3] = pcy + psy * 0.5f;
    float lg = H[(48 + a) * NPOS + p];
    SCg[(size_t)b * NANCH + n] = 1.0f / (1.0f + expf(-lg));
  }
}

// ---------------------------------------------------------------------------
// NMS: rank sort + IoU bitmask + wave-parallel greedy scan.  512 thr, 66 KB.
// ---------------------------------------------------------------------------
__device__ inline unsigned long long shfl64(unsigned long long v, int lane) {
  int lo = __shfl((int)(unsigned)(v & 0xffffffffULL), lane, 64);
  int hi = __shfl((int)(unsigned)(v >> 32), lane, 64);
  return ((unsigned long long)(unsigned)hi << 32) | (unsigned)lo;
}

__global__ __launch_bounds__(512, 4) void nms_kernel(
    const float* __restrict__ BXg, const float* __restrict__ SCg,
    float* __restrict__ out) {
  __shared__ float smem[16576];
  unsigned long long* KEY = (unsigned long long*)smem;          // [588]
  float* SB  = smem + 1176;                                     // [588*4]
  float* SSc = smem + 3528;                                     // [588]
  float* AR  = smem + 4116;                                     // [588]
  unsigned long long* ADJ = (unsigned long long*)(smem + 4704); // [588*10]
  int* KEEP = (int*)(smem + 16464);                             // [100]
  int* CNT  = (int*)(smem + 16564);
  const int b = blockIdx.x, t = threadIdx.x;
  const float* scb = SCg + (size_t)b * NANCH;
  const float4* bxb = (const float4*)(BXg + (size_t)b * (NANCH * 4));
  for (int i = t; i < NANCH; i += 512) {
    unsigned u = __float_as_uint(scb[i]);
    u = (u & 0x80000000u) ? ~u : (u | 0x80000000u);
    u = ~u;
    KEY[i] = ((unsigned long long)u << 32) | (unsigned)i;
  }
  __syncthreads();
  for (int i = t; i < NANCH; i += 512) {
    unsigned long long k = KEY[i];
    int rank = 0;
    for (int j = 0; j < NANCH; ++j) rank += (KEY[j] < k) ? 1 : 0;
    float4 bx = bxb[i];
    ((float4*)SB)[rank] = bx;
    SSc[rank] = scb[i];
    AR[rank] = (bx.z - bx.x) * (bx.w - bx.y);
  }
  __syncthreads();
  const float4* SB4 = (const float4*)SB;
  for (int task = t; task < NANCH * 10; task += 512) {
    int i = task % NANCH, w = task / NANCH;
    float4 a = SB4[i];
    float aar = AR[i];
    int jbase = w * 64;
    int jend = NANCH - jbase; if (jend > 64) jend = 64;
    unsigned long long bits = 0;
    for (int bi = 0; bi < jend; ++bi) {
      int j = jbase + bi;
      float4 bb = SB4[j];
      float ltx = fmaxf(a.x, bb.x), lty = fmaxf(a.y, bb.y);
      float rbx = fminf(a.z, bb.z), rby = fminf(a.w, bb.w);
      float wx = rbx - ltx; wx = wx > 0.f ? wx : 0.f;
      float wy = rby - lty; wy = wy > 0.f ? wy : 0.f;
      float inter = wx * wy;
      float iou = inter / (aar + AR[j] - inter + 1e-9f);
      if (iou > 0.5f) bits |= (1ULL << bi);
    }
    ADJ[i * 10 + w] = bits;
  }
  __syncthreads();
  if (t < 64) {
    unsigned long long valid = 0, supp = 0;
    if (t < 10) {
      int jbase = t * 64;
      int jend = NANCH - jbase; if (jend > 64) jend = 64;
      for (int k = 0; k < jend; ++k)
        valid |= (unsigned long long)(SSc[jbase + k] > 0.3f ? 1 : 0) << k;
    }
    int cnt = 0;
    for (int w = 0; w < 10 && cnt < 100; ++w) {
      unsigned long long cur = shfl64(valid, w) & ~shfl64(supp, w);
      while (cur && cnt < 100) {
        int bpos = (int)__builtin_ctzll(cur);
        int i = w * 64 + bpos;
        if (t == 0) KEEP[cnt] = i;
        cnt++;
        unsigned long long a = (t < 10) ? ADJ[i * 10 + t] : 0ULL;
        if (t < w) a = 0ULL;
        else if (t == w) a &= ~((2ULL << bpos) - 1ULL);
        supp |= a;
        unsigned long long aw = shfl64(a, w);
        cur &= ~aw;
        cur &= ~(1ULL << bpos);
      }
    }
    if (t == 0) *CNT = cnt;
  }
  __syncthreads();
  int cnt = *CNT;
  if (t < 100) {
    float4 bx = make_float4(0.f, 0.f, 0.f, 0.f);
    float s = 0.f, vld = 0.f;
    if (t < cnt) {
      int i = KEEP[t];
      bx = SB4[i];
      s = SSc[i];
      vld = 1.f;
    }
    float* ob = out + (size_t)b * 600 + t * 6;
    ob[0] = bx.x; ob[1] = bx.y; ob[2] = bx.z; ob[3] = bx.w;
    ob[4] = s;    ob[5] = vld;
  }
}

// ---------------------------------------------------------------------------
extern "C" void kernel_launch(void* const* d_in, const int* in_sizes, int n_in,
                              void* d_out, int out_size, void* d_ws, size_t ws_size,
                              hipStream_t stream) {
  const float* feat = (const float*)d_in[0];
  const float* w1  = (const float*)d_in[1];
  const float* b1  = (const float*)d_in[2];
  const float* g1  = (const float*)d_in[3];
  const float* be1 = (const float*)d_in[4];
  const float* mu1 = (const float*)d_in[5];
  const float* v1  = (const float*)d_in[6];
  const float* w2  = (const float*)d_in[7];
  const float* b2  = (const float*)d_in[8];
  const float* g2  = (const float*)d_in[9];
  const float* be2 = (const float*)d_in[10];
  const float* mu2 = (const float*)d_in[11];
  const float* v2  = (const float*)d_in[12];
  const float* w3  = (const float*)d_in[13];
  const float* b3  = (const float*)d_in[14];
  const float* g3  = (const float*)d_in[15];
  const float* be3 = (const float*)d_in[16];
  const float* mu3 = (const float*)d_in[17];
  const float* v3  = (const float*)d_in[18];
  const float* w4  = (const float*)d_in[19];
  const float* b4  = (const float*)d_in[20];
  const float* g4  = (const float*)d_in[21];
  const float* be4 = (const float*)d_in[22];
  const float* mu4 = (const float*)d_in[23];
  const float* v4  = (const float*)d_in[24];
  const float* wcls = (const float*)d_in[25];
  const float* bcls = (const float*)d_in[26];
  const float* wbox = (const float*)d_in[27];
  const float* bbox = (const float*)d_in[28];

  const int B = in_sizes[0] / (512 * NPOS);
  float* ws  = (float*)d_ws;
  size_t xsz = (size_t)B * 256 * NPOS;
  float* xa  = ws;
  float* xb  = xa + xsz;
  float* w1t = xb + xsz;
  float* w2t = w1t + 131072;
  float* w3t = w2t + 589824;
  float* w4t = w3t + 589824;
  float* wbt = w4t + 589824;
  float* wct = wbt + 110592;
  float* BXg = wct + 27648;
  float* SCg = BXg + (size_t)B * (NANCH * 4);

  transpose_all<<<(2038784 + 255) / 256, 256, 0, stream>>>(
      w1, w2, w3, w4, wbox, wcls, w1t, w2t, w3t, w4t, wbt, wct);
  conv1x1_bn<<<2 * B, 512, 0, stream>>>(feat, w1t, b1, g1, be1, mu1, v1, xa);
  conv3x3_bn<<<2 * B, 512, 0, stream>>>(xa, w2t, b2, g2, be2, mu2, v2, xb);
  conv3x3_bn<<<2 * B, 512, 0, stream>>>(xb, w3t, b3, g3, be3, mu3, v3, xa);
  conv3x3_bn<<<2 * B, 512, 0, stream>>>(xa, w4t, b4, g4, be4, mu4, v4, xb);
  heads_decode<<<B, 512, 0, stream>>>(xb, wbt, wct, bbox, bcls, BXg, SCg);
  nms_kernel<<<B, 512, 0, stream>>>(BXg, SCg, (float*)d_out);
}

// Round 5
// 958.462 us; speedup vs baseline: 2.4133x; 1.0377x over previous
//
#include <hip/hip_runtime.h>
#include <cmath>
#include <cstdint>

#define NPOS 49
#define NANCH 588

// ---------------------------------------------------------------------------
// Weight transposes.
// w1: [256][512] -> float4-interleaved [(c/4)*256 + o][c%4]  (4 ch per load)
// wNt[ck*256+o] = wN[o*2304+ck]               (3x3 convs, [c*9+k][o])
// wbt[ck*48+o], wct[ck*12+o]                  (heads)
// ---------------------------------------------------------------------------
__global__ void transpose_all(
    const float* __restrict__ w1, const float* __restrict__ w2,
    const float* __restrict__ w3, const float* __restrict__ w4,
    const float* __restrict__ wb, const float* __restrict__ wc,
    float* __restrict__ w1t, float* __restrict__ w2t, float* __restrict__ w3t,
    float* __restrict__ w4t, float* __restrict__ wbt, float* __restrict__ wct) {
  int idx = blockIdx.x * blockDim.x + threadIdx.x;
  if (idx < 131072) {
    int o = idx / 512, c = idx % 512;
    w1t[((c >> 2) * 256 + o) * 4 + (c & 3)] = w1[idx];
    return;
  }
  idx -= 131072;
  if (idx < 589824) { int o = idx / 2304, ck = idx % 2304; w2t[ck * 256 + o] = w2[idx]; return; }
  idx -= 589824;
  if (idx < 589824) { int o = idx / 2304, ck = idx % 2304; w3t[ck * 256 + o] = w3[idx]; return; }
  idx -= 589824;
  if (idx < 589824) { int o = idx / 2304, ck = idx % 2304; w4t[ck * 256 + o] = w4[idx]; return; }
  idx -= 589824;
  if (idx < 110592) { int o = idx / 2304, ck = idx % 2304; wbt[ck * 48 + o] = wb[idx]; return; }
  idx -= 110592;
  if (idx < 27648)  { int o = idx / 2304, ck = idx % 2304; wct[ck * 12 + o] = wc[idx]; return; }
}

// ---------------------------------------------------------------------------
// conv 1x1 (512 -> 256) + bias + BN + ReLU.
// Grid = 2*B: block = (image, o-half of 128).  512 thr = 128 o x 4-way K-split.
// Weights float4-interleaved (4 ch/load), prefetched one quad ahead.
// __launch_bounds__(512,2): VGPR cap 128 (min-blocks=4 -> cap 64 spilled; R2/R3).
// ---------------------------------------------------------------------------
__global__ __launch_bounds__(512, 2) void conv1x1_bn(
    const float* __restrict__ wt_f, const float* __restrict__ in,
    const float* __restrict__ bias, const float* __restrict__ gg,
    const float* __restrict__ be, const float* __restrict__ mu,
    const float* __restrict__ var, float* __restrict__ out) {
  __shared__ float smem[256 * 52];
  const int blk = blockIdx.x, t = threadIdx.x;
  const int b = blk >> 1, oh = blk & 1;
  const int o = t & 127, cg = t >> 7;      // cg in 0..3
  const int og = oh * 128 + o;
  const float* inb = in + (size_t)b * (512 * NPOS);
  const float4* wq = (const float4*)wt_f;  // [128 quads][256 o]
  float acc[NPOS];
#pragma unroll
  for (int p = 0; p < NPOS; ++p) acc[p] = 0.f;
  for (int h = 0; h < 2; ++h) {
    __syncthreads();                       // WAR vs previous phase compute
    const int q0 = h * 64 + cg * 16;
    float4 wcur = wq[q0 * 256 + og];       // issue before staging -> overlap
    for (int i = t; i < 256 * NPOS; i += 512) {
      int c = i / NPOS, p = i - c * NPOS;
      smem[c * 52 + p] = inb[(h * 256 + c) * NPOS + p];
    }
    __syncthreads();
    for (int q = q0; q < q0 + 16; ++q) {
      int nq = (q + 1 < q0 + 16) ? q + 1 : q;
      float4 wnxt = wq[nq * 256 + og];     // prefetch next quad
      const int clbase = (q - h * 64) * 4;
#pragma unroll
      for (int j = 0; j < 4; ++j) {
        float wv = (j == 0) ? wcur.x : (j == 1) ? wcur.y : (j == 2) ? wcur.z : wcur.w;
        const float4* tr = (const float4*)(smem + (clbase + j) * 52);
#pragma unroll
        for (int jj = 0; jj < 12; ++jj) {
          float4 qv = tr[jj];
          acc[4 * jj + 0] = fmaf(wv, qv.x, acc[4 * jj + 0]);
          acc[4 * jj + 1] = fmaf(wv, qv.y, acc[4 * jj + 1]);
          acc[4 * jj + 2] = fmaf(wv, qv.z, acc[4 * jj + 2]);
          acc[4 * jj + 3] = fmaf(wv, qv.w, acc[4 * jj + 3]);
        }
        acc[48] = fmaf(wv, smem[(clbase + j) * 52 + 48], acc[48]);
      }
      wcur = wnxt;
    }
  }
  __syncthreads();
  float* P0 = smem;
  float* P1 = smem + 6272;
  if (cg == 1) { for (int p = 0; p < NPOS; ++p) P0[o * NPOS + p] = acc[p]; }
  if (cg == 3) { for (int p = 0; p < NPOS; ++p) P1[o * NPOS + p] = acc[p]; }
  __syncthreads();
  if (cg == 0) { for (int p = 0; p < NPOS; ++p) acc[p] += P0[o * NPOS + p]; }
  if (cg == 2) { for (int p = 0; p < NPOS; ++p) acc[p] += P1[o * NPOS + p]; }
  __syncthreads();
  if (cg == 2) { for (int p = 0; p < NPOS; ++p) P0[o * NPOS + p] = acc[p]; }
  __syncthreads();
  if (cg == 0) {
    float scale = gg[og] / sqrtf(var[og] + 1e-5f);
    float add = (bias[og] - mu[og]) * scale + be[og];
#pragma unroll
    for (int p = 0; p < NPOS; ++p) {
      float v = (acc[p] + P0[o * NPOS + p]) * scale + add;
      P1[o * NPOS + p] = v > 0.f ? v : 0.f;
    }
  }
  __syncthreads();
  float* outb = out + (size_t)b * (256 * NPOS) + oh * (128 * NPOS);
  for (int i = t; i < 128 * NPOS; i += 512) outb[i] = P1[i];
}

// ---------------------------------------------------------------------------
// conv 3x3 pad1 (256 -> 256) + bias + BN + ReLU.
// Grid = 2*B: block = (image, o-half of 128).  512 thr = 128 o x 4-way K-split.
// Weights prefetched one channel ahead (dep distance = 441 FMAs >> L2 latency);
// phase-first weights issued before staging so the load overlaps the copy.
// ---------------------------------------------------------------------------
#define LOADROW(dst, base, rr)                                          \
  do {                                                                  \
    const float4* q4_ = (const float4*)((base) + (rr) * 12);            \
    float4 q0_ = q4_[0], q1_ = q4_[1], q2_ = q4_[2];                    \
    dst[0] = q0_.x; dst[1] = q0_.y; dst[2] = q0_.z; dst[3] = q0_.w;     \
    dst[4] = q1_.x; dst[5] = q1_.y; dst[6] = q1_.z; dst[7] = q1_.w;     \
    dst[8] = q2_.x;                                                     \
  } while (0)

__global__ __launch_bounds__(512, 2) void conv3x3_bn(
    const float* __restrict__ in, const float* __restrict__ wt,
    const float* __restrict__ bias, const float* __restrict__ gg,
    const float* __restrict__ be, const float* __restrict__ mu,
    const float* __restrict__ var, float* __restrict__ out) {
  __shared__ float smem[128 * 108];  // 55,296 B
  const int blk = blockIdx.x, t = threadIdx.x;
  const int b = blk >> 1, oh = blk & 1;
  const int o = t & 127, cg = t >> 7;      // cg in 0..3
  const int og = oh * 128 + o;
  const float* inb = in + (size_t)b * (256 * NPOS);
  for (int i = t; i < 128 * 108; i += 512) smem[i] = 0.f;  // borders stay 0
  float acc[NPOS];
#pragma unroll
  for (int p = 0; p < NPOS; ++p) acc[p] = 0.f;
  for (int h = 0; h < 2; ++h) {
    __syncthreads();  // zero done / previous compute done (WAR)
    const int cb = h * 128 + cg * 32;      // first absolute channel for this cg
    float wc_[9];
#pragma unroll
    for (int k = 0; k < 9; ++k) wc_[k] = wt[(cb * 9 + k) * 256 + og];  // overlap staging
    for (int i = t; i < 128 * NPOS; i += 512) {
      int c = i / NPOS, p = i - c * NPOS, y = p / 7, x = p - y * 7;
      smem[c * 108 + (y + 1) * 12 + (x + 1)] = inb[(h * 128 + c) * NPOS + p];
    }
    __syncthreads();
    for (int cl = 0; cl < 32; ++cl) {
      const int c = cb + cl;
      const int cn = (cl + 1 < 32) ? c + 1 : c;
      float wn_[9];
#pragma unroll
      for (int k = 0; k < 9; ++k) wn_[k] = wt[(cn * 9 + k) * 256 + og];  // prefetch
      const float* tb = smem + (cg * 32 + cl) * 108;
      float R[3][9];
      LOADROW(R[0], tb, 0);
      LOADROW(R[1], tb, 1);
#pragma unroll
      for (int y = 0; y < 7; ++y) {
        LOADROW(R[(y + 2) % 3], tb, y + 2);
        const float* r0 = R[y % 3];
        const float* r1 = R[(y + 1) % 3];
        const float* r2 = R[(y + 2) % 3];
#pragma unroll
        for (int x = 0; x < 7; ++x) {
          float s = acc[y * 7 + x];
          s = fmaf(wc_[0], r0[x], s);
          s = fmaf(wc_[1], r0[x + 1], s);
          s = fmaf(wc_[2], r0[x + 2], s);
          s = fmaf(wc_[3], r1[x], s);
          s = fmaf(wc_[4], r1[x + 1], s);
          s = fmaf(wc_[5], r1[x + 2], s);
          s = fmaf(wc_[6], r2[x], s);
          s = fmaf(wc_[7], r2[x + 1], s);
          s = fmaf(wc_[8], r2[x + 2], s);
          acc[y * 7 + x] = s;
        }
      }
#pragma unroll
      for (int k = 0; k < 9; ++k) wc_[k] = wn_[k];
    }
  }
  __syncthreads();
  float* P0 = smem;
  float* P1 = smem + 6272;
  if (cg == 1) { for (int p = 0; p < NPOS; ++p) P0[o * NPOS + p] = acc[p]; }
  if (cg == 3) { for (int p = 0; p < NPOS; ++p) P1[o * NPOS + p] = acc[p]; }
  __syncthreads();
  if (cg == 0) { for (int p = 0; p < NPOS; ++p) acc[p] += P0[o * NPOS + p]; }
  if (cg == 2) { for (int p = 0; p < NPOS; ++p) acc[p] += P1[o * NPOS + p]; }
  __syncthreads();
  if (cg == 2) { for (int p = 0; p < NPOS; ++p) P0[o * NPOS + p] = acc[p]; }
  __syncthreads();
  if (cg == 0) {
    float scale = gg[og] / sqrtf(var[og] + 1e-5f);
    float add = (bias[og] - mu[og]) * scale + be[og];
#pragma unroll
    for (int p = 0; p < NPOS; ++p) {
      float v = (acc[p] + P0[o * NPOS + p]) * scale + add;
      P1[o * NPOS + p] = v > 0.f ? v : 0.f;
    }
  }
  __syncthreads();
  float* outb = out + (size_t)b * (256 * NPOS) + oh * (128 * NPOS);
  for (int i = t; i < 128 * NPOS; i += 512) outb[i] = P1[i];
}

// ---------------------------------------------------------------------------
// Heads (box 48ch + cls 12ch, 3x3 pad1) + decode + sigmoid.
// 512 threads: 60 out-ch x 8-way K-split.  Weights prefetched one ch ahead.
// ---------------------------------------------------------------------------
__global__ __launch_bounds__(512, 2) void heads_decode(
    const float* __restrict__ in, const float* __restrict__ wbt,
    const float* __restrict__ wct, const float* __restrict__ bb,
    const float* __restrict__ bc, float* __restrict__ BXg,
    float* __restrict__ SCg) {
  __shared__ float smem[256 * 108];
  const int b = blockIdx.x, t = threadIdx.x;
  for (int i = t; i < 256 * 108; i += 512) smem[i] = 0.f;
  __syncthreads();
  const float* inb = in + (size_t)b * (256 * NPOS);
  for (int i = t; i < 256 * NPOS; i += 512) {
    int c = i / NPOS, p = i - c * NPOS, y = p / 7, x = p - y * 7;
    smem[c * 108 + (y + 1) * 12 + (x + 1)] = inb[i];
  }
  __syncthreads();
  float acc[NPOS];
#pragma unroll
  for (int p = 0; p < NPOS; ++p) acc[p] = 0.f;
  int o = 0, cg = 0;
  if (t < 480) {
    o = t % 60; cg = t / 60;  // 8-way K-split, 32 c each
    const float* wbase; int wstr;
    if (o < 48) { wbase = wbt + o; wstr = 48; }
    else        { wbase = wct + (o - 48); wstr = 12; }
    const int c0 = cg * 32;
    float wc_[9];
#pragma unroll
    for (int k = 0; k < 9; ++k) wc_[k] = wbase[(c0 * 9 + k) * wstr];
    for (int c = c0; c < c0 + 32; ++c) {
      int cn = (c + 1 < c0 + 32) ? c + 1 : c;
      float wn_[9];
#pragma unroll
      for (int k = 0; k < 9; ++k) wn_[k] = wbase[(cn * 9 + k) * wstr];  // prefetch
      const float* tb = smem + c * 108;
      float R[3][9];
      LOADROW(R[0], tb, 0);
      LOADROW(R[1], tb, 1);
#pragma unroll
      for (int y = 0; y < 7; ++y) {
        LOADROW(R[(y + 2) % 3], tb, y + 2);
        const float* r0 = R[y % 3];
        const float* r1 = R[(y + 1) % 3];
        const float* r2 = R[(y + 2) % 3];
#pragma unroll
        for (int x = 0; x < 7; ++x) {
          float s = acc[y * 7 + x];
          s = fmaf(wc_[0], r0[x], s);
          s = fmaf(wc_[1], r0[x + 1], s);
          s = fmaf(wc_[2], r0[x + 2], s);
          s = fmaf(wc_[3], r1[x], s);
          s = fmaf(wc_[4], r1[x + 1], s);
          s = fmaf(wc_[5], r1[x + 2], s);
          s = fmaf(wc_[6], r2[x], s);
          s = fmaf(wc_[7], r2[x + 1], s);
          s = fmaf(wc_[8], r2[x + 2], s);
          acc[y * 7 + x] = s;
        }
      }
#pragma unroll
      for (int k = 0; k < 9; ++k) wc_[k] = wn_[k];
    }
  }
  __syncthreads();
  float* part = smem;            // [7][60][49]
  float* H = smem + 7 * 2940;    // [60][49]
  if (t < 480 && cg > 0) {
#pragma unroll
    for (int p = 0; p < NPOS; ++p) part[(cg - 1) * 2940 + o * NPOS + p] = acc[p];
  }
  __syncthreads();
  if (t < 60) {  // cg == 0
    float bsum = (o < 48) ? bb[o] : bc[o - 48];
#pragma unroll
    for (int p = 0; p < NPOS; ++p) {
      float v = acc[p] + bsum;
      for (int g = 0; g < 7; ++g) v += part[g * 2940 + o * NPOS + p];
      H[o * NPOS + p] = v;
    }
  }
  __syncthreads();
  const float scl[4] = {0.3f, 0.5f, 0.7f, 0.9f};
  const float rat[3] = {0.7f, 1.0f, 1.3f};
  for (int n = t; n < NANCH; n += 512) {
    int p = n / 12, a = n - p * 12;
    int ph = p / 7, pw = p - ph * 7;
    float cx = (ph + 0.5f) / 7.0f;
    float cy = (pw + 0.5f) / 7.0f;
    int s = a / 3, r = a - s * 3;
    float rt = sqrtf(rat[r]);
    float wsz = scl[s] * rt, hsz = scl[s] / rt;
    float x1 = cx + (-wsz) * 0.5f, y1 = cy + (-hsz) * 0.5f;
    float x2 = cx + wsz * 0.5f,    y2 = cy + hsz * 0.5f;
    float acx = (x1 + x2) * 0.5f,  acy = (y1 + y2) * 0.5f;
    float asx = x2 - x1,           asy = y2 - y1;
    float bp0 = H[(a * 4 + 0) * NPOS + p];
    float bp1 = H[(a * 4 + 1) * NPOS + p];
    float bp2 = H[(a * 4 + 2) * NPOS + p];
    float bp3 = H[(a * 4 + 3) * NPOS + p];
    float pcx = bp0 * asx + acx;
    float pcy = bp1 * asy + acy;
    float psx = expf(bp2) * asx;
    float psy = expf(bp3) * asy;
    float* bx = BXg + (size_t)b * (NANCH * 4) + n * 4;
    bx[0] = pcx - psx * 0.5f;
    bx[1] = pcy - psy * 0.5f;
    bx[2] = pcx + psx * 0.5f;
    bx[3] = pcy + psy * 0.5f;
    float lg = H[(48 + a) * NPOS + p];
    SCg[(size_t)b * NANCH + n] = 1.0f / (1.0f + expf(-lg));
  }
}

// ---------------------------------------------------------------------------
// NMS: rank sort + IoU bitmask + wave-parallel greedy scan.  512 thr, 66 KB.
// ---------------------------------------------------------------------------
__device__ inline unsigned long long shfl64(unsigned long long v, int lane) {
  int lo = __shfl((int)(unsigned)(v & 0xffffffffULL), lane, 64);
  int hi = __shfl((int)(unsigned)(v >> 32), lane, 64);
  return ((unsigned long long)(unsigned)hi << 32) | (unsigned)lo;
}

__global__ __launch_bounds__(512, 4) void nms_kernel(
    const float* __restrict__ BXg, const float* __restrict__ SCg,
    float* __restrict__ out) {
  __shared__ float smem[16576];
  unsigned long long* KEY = (unsigned long long*)smem;          // [588]
  float* SB  = smem + 1176;                                     // [588*4]
  float* SSc = smem + 3528;                                     // [588]
  float* AR  = smem + 4116;                                     // [588]
  unsigned long long* ADJ = (unsigned long long*)(smem + 4704); // [588*10]
  int* KEEP = (int*)(smem + 16464);                             // [100]
  int* CNT  = (int*)(smem + 16564);
  const int b = blockIdx.x, t = threadIdx.x;
  const float* scb = SCg + (size_t)b * NANCH;
  const float4* bxb = (const float4*)(BXg + (size_t)b * (NANCH * 4));
  for (int i = t; i < NANCH; i += 512) {
    unsigned u = __float_as_uint(scb[i]);
    u = (u & 0x80000000u) ? ~u : (u | 0x80000000u);
    u = ~u;
    KEY[i] = ((unsigned long long)u << 32) | (unsigned)i;
  }
  __syncthreads();
  for (int i = t; i < NANCH; i += 512) {
    unsigned long long k = KEY[i];
    int rank = 0;
    for (int j = 0; j < NANCH; ++j) rank += (KEY[j] < k) ? 1 : 0;
    float4 bx = bxb[i];
    ((float4*)SB)[rank] = bx;
    SSc[rank] = scb[i];
    AR[rank] = (bx.z - bx.x) * (bx.w - bx.y);
  }
  __syncthreads();
  const float4* SB4 = (const float4*)SB;
  for (int task = t; task < NANCH * 10; task += 512) {
    int i = task % NANCH, w = task / NANCH;
    float4 a = SB4[i];
    float aar = AR[i];
    int jbase = w * 64;
    int jend = NANCH - jbase; if (jend > 64) jend = 64;
    unsigned long long bits = 0;
    for (int bi = 0; bi < jend; ++bi) {
      int j = jbase + bi;
      float4 bb = SB4[j];
      float ltx = fmaxf(a.x, bb.x), lty = fmaxf(a.y, bb.y);
      float rbx = fminf(a.z, bb.z), rby = fminf(a.w, bb.w);
      float wx = rbx - ltx; wx = wx > 0.f ? wx : 0.f;
      float wy = rby - lty; wy = wy > 0.f ? wy : 0.f;
      float inter = wx * wy;
      float iou = inter / (aar + AR[j] - inter + 1e-9f);
      if (iou > 0.5f) bits |= (1ULL << bi);
    }
    ADJ[i * 10 + w] = bits;
  }
  __syncthreads();
  if (t < 64) {
    unsigned long long valid = 0, supp = 0;
    if (t < 10) {
      int jbase = t * 64;
      int jend = NANCH - jbase; if (jend > 64) jend = 64;
      for (int k = 0; k < jend; ++k)
        valid |= (unsigned long long)(SSc[jbase + k] > 0.3f ? 1 : 0) << k;
    }
    int cnt = 0;
    for (int w = 0; w < 10 && cnt < 100; ++w) {
      unsigned long long cur = shfl64(valid, w) & ~shfl64(supp, w);
      while (cur && cnt < 100) {
        int bpos = (int)__builtin_ctzll(cur);
        int i = w * 64 + bpos;
        if (t == 0) KEEP[cnt] = i;
        cnt++;
        unsigned long long a = (t < 10) ? ADJ[i * 10 + t] : 0ULL;
        if (t < w) a = 0ULL;
        else if (t == w) a &= ~((2ULL << bpos) - 1ULL);
        supp |= a;
        unsigned long long aw = shfl64(a, w);
        cur &= ~aw;
        cur &= ~(1ULL << bpos);
      }
    }
    if (t == 0) *CNT = cnt;
  }
  __syncthreads();
  int cnt = *CNT;
  if (t < 100) {
    float4 bx = make_float4(0.f, 0.f, 0.f, 0.f);
    float s = 0.f, vld = 0.f;
    if (t < cnt) {
      int i = KEEP[t];
      bx = SB4[i];
      s = SSc[i];
      vld = 1.f;
    }
    float* ob = out + (size_t)b * 600 + t * 6;
    ob[0] = bx.x; ob[1] = bx.y; ob[2] = bx.z; ob[3] = bx.w;
    ob[4] = s;    ob[5] = vld;
  }
}

// ---------------------------------------------------------------------------
extern "C" void kernel_launch(void* const* d_in, const int* in_sizes, int n_in,
                              void* d_out, int out_size, void* d_ws, size_t ws_size,
                              hipStream_t stream) {
  const float* feat = (const float*)d_in[0];
  const float* w1  = (const float*)d_in[1];
  const float* b1  = (const float*)d_in[2];
  const float* g1  = (const float*)d_in[3];
  const float* be1 = (const float*)d_in[4];
  const float* mu1 = (const float*)d_in[5];
  const float* v1  = (const float*)d_in[6];
  const float* w2  = (const float*)d_in[7];
  const float* b2  = (const float*)d_in[8];
  const float* g2  = (const float*)d_in[9];
  const float* be2 = (const float*)d_in[10];
  const float* mu2 = (const float*)d_in[11];
  const float* v2  = (const float*)d_in[12];
  const float* w3  = (const float*)d_in[13];
  const float* b3  = (const float*)d_in[14];
  const float* g3  = (const float*)d_in[15];
  const float* be3 = (const float*)d_in[16];
  const float* mu3 = (const float*)d_in[17];
  const float* v3  = (const float*)d_in[18];
  const float* w4  = (const float*)d_in[19];
  const float* b4  = (const float*)d_in[20];
  const float* g4  = (const float*)d_in[21];
  const float* be4 = (const float*)d_in[22];
  const float* mu4 = (const float*)d_in[23];
  const float* v4  = (const float*)d_in[24];
  const float* wcls = (const float*)d_in[25];
  const float* bcls = (const float*)d_in[26];
  const float* wbox = (const float*)d_in[27];
  const float* bbox = (const float*)d_in[28];

  const int B = in_sizes[0] / (512 * NPOS);
  float* ws  = (float*)d_ws;
  size_t xsz = (size_t)B * 256 * NPOS;
  float* xa  = ws;
  float* xb  = xa + xsz;
  float* w1t = xb + xsz;
  float* w2t = w1t + 131072;
  float* w3t = w2t + 589824;
  float* w4t = w3t + 589824;
  float* wbt = w4t + 589824;
  float* wct = wbt + 110592;
  float* BXg = wct + 27648;
  float* SCg = BXg + (size_t)B * (NANCH * 4);

  transpose_all<<<(2038784 + 255) / 256, 256, 0, stream>>>(
      w1, w2, w3, w4, wbox, wcls, w1t, w2t, w3t, w4t, wbt, wct);
  conv1x1_bn<<<2 * B, 512, 0, stream>>>(w1t, feat, b1, g1, be1, mu1, v1, xa);
  conv3x3_bn<<<2 * B, 512, 0, stream>>>(xa, w2t, b2, g2, be2, mu2, v2, xb);
  conv3x3_bn<<<2 * B, 512, 0, stream>>>(xb, w3t, b3, g3, be3, mu3, v3, xa);
  conv3x3_bn<<<2 * B, 512, 0, stream>>>(xa, w4t, b4, g4, be4, mu4, v4, xb);
  heads_decode<<<B, 512, 0, stream>>>(xb, wbt, wct, bbox, bcls, BXg, SCg);
  nms_kernel<<<B, 512, 0, stream>>>(BXg, SCg, (float*)d_out);
}

// Round 6
// 895.901 us; speedup vs baseline: 2.5819x; 1.0698x over previous
//
#include <hip/hip_runtime.h>
#include <cmath>
#include <cstdint>

#define NPOS 49
#define NANCH 588

// ---------------------------------------------------------------------------
// Weight transposes.
// w1:  [256][512] -> float4-interleaved w1t[q*256+o][4] = w1[o][4q..4q+3]
// w2/3/4: [o][c][3][3] -> k-contiguous wNt[(c*256+o)*12 + k]  (k<9, pad 12)
// heads:  wbt[ck*48+o], wct[ck*12+o]
// ---------------------------------------------------------------------------
__global__ void transpose_all(
    const float* __restrict__ w1, const float* __restrict__ w2,
    const float* __restrict__ w3, const float* __restrict__ w4,
    const float* __restrict__ wb, const float* __restrict__ wc,
    float* __restrict__ w1t, float* __restrict__ w2t, float* __restrict__ w3t,
    float* __restrict__ w4t, float* __restrict__ wbt, float* __restrict__ wct) {
  int idx = blockIdx.x * blockDim.x + threadIdx.x;
  if (idx < 131072) {
    int o = idx / 512, c = idx % 512;
    w1t[((c >> 2) * 256 + o) * 4 + (c & 3)] = w1[idx];
    return;
  }
  idx -= 131072;
  if (idx < 589824) {
    int o = idx / 2304, ck = idx % 2304, c = ck / 9, k = ck - c * 9;
    w2t[(c * 256 + o) * 12 + k] = w2[idx]; return;
  }
  idx -= 589824;
  if (idx < 589824) {
    int o = idx / 2304, ck = idx % 2304, c = ck / 9, k = ck - c * 9;
    w3t[(c * 256 + o) * 12 + k] = w3[idx]; return;
  }
  idx -= 589824;
  if (idx < 589824) {
    int o = idx / 2304, ck = idx % 2304, c = ck / 9, k = ck - c * 9;
    w4t[(c * 256 + o) * 12 + k] = w4[idx]; return;
  }
  idx -= 589824;
  if (idx < 110592) { int o = idx / 2304, ck = idx % 2304; wbt[ck * 48 + o] = wb[idx]; return; }
  idx -= 110592;
  if (idx < 27648)  { int o = idx / 2304, ck = idx % 2304; wct[ck * 12 + o] = wc[idx]; return; }
}

// ---------------------------------------------------------------------------
// conv 1x1 (512 -> 256) + bias + BN + ReLU.  Grid = B (block = whole image).
// 512 thr = 128 slots x 4-way K-split; thread computes o = slot and slot+128.
// Each LDS tile row read feeds 2 output channels (halves LDS issue per FMA).
// ---------------------------------------------------------------------------
__global__ __launch_bounds__(512, 1) void conv1x1_bn(
    const float* __restrict__ in, const float* __restrict__ wt_f,
    const float* __restrict__ bias, const float* __restrict__ gg,
    const float* __restrict__ be, const float* __restrict__ mu,
    const float* __restrict__ var, float* __restrict__ out) {
  __shared__ float smem[512 * 52];  // 106,496 B -> 1 block/CU
  const int b = blockIdx.x, t = threadIdx.x;
  const int slot = t & 127, cg = t >> 7;   // cg in 0..3
  const int o0 = slot, o1 = slot + 128;
  const float* inb = in + (size_t)b * (512 * NPOS);
  const float4* wq = (const float4*)wt_f;  // [128 quads][256 o]
  const int q0 = cg * 32;                  // 32 quads (128 channels) per cg
  float4 wca = wq[q0 * 256 + o0];          // issue before staging (overlap)
  float4 wcb = wq[q0 * 256 + o1];
  for (int i = t; i < 512 * NPOS; i += 512) {
    int c = i / NPOS, p = i - c * NPOS;
    smem[c * 52 + p] = inb[i];
  }
  float acc0[NPOS], acc1[NPOS];
#pragma unroll
  for (int p = 0; p < NPOS; ++p) { acc0[p] = 0.f; acc1[p] = 0.f; }
  __syncthreads();
  for (int q = q0; q < q0 + 32; ++q) {
    int nq = (q + 1 < q0 + 32) ? q + 1 : q;
    float4 wna = wq[nq * 256 + o0];        // prefetch next quad
    float4 wnb = wq[nq * 256 + o1];
#pragma unroll
    for (int j = 0; j < 4; ++j) {
      float wa = (j == 0) ? wca.x : (j == 1) ? wca.y : (j == 2) ? wca.z : wca.w;
      float wb2 = (j == 0) ? wcb.x : (j == 1) ? wcb.y : (j == 2) ? wcb.z : wcb.w;
      const float* row = smem + (q * 4 + j) * 52;
      const float4* tr = (const float4*)row;
#pragma unroll
      for (int jj = 0; jj < 12; ++jj) {
        float4 qv = tr[jj];
        acc0[4 * jj + 0] = fmaf(wa, qv.x, acc0[4 * jj + 0]);
        acc0[4 * jj + 1] = fmaf(wa, qv.y, acc0[4 * jj + 1]);
        acc0[4 * jj + 2] = fmaf(wa, qv.z, acc0[4 * jj + 2]);
        acc0[4 * jj + 3] = fmaf(wa, qv.w, acc0[4 * jj + 3]);
        acc1[4 * jj + 0] = fmaf(wb2, qv.x, acc1[4 * jj + 0]);
        acc1[4 * jj + 1] = fmaf(wb2, qv.y, acc1[4 * jj + 1]);
        acc1[4 * jj + 2] = fmaf(wb2, qv.z, acc1[4 * jj + 2]);
        acc1[4 * jj + 3] = fmaf(wb2, qv.w, acc1[4 * jj + 3]);
      }
      float s48 = row[48];
      acc0[48] = fmaf(wa, s48, acc0[48]);
      acc1[48] = fmaf(wb2, s48, acc1[48]);
    }
    wca = wna; wcb = wnb;
  }
  __syncthreads();
  float* P0 = smem;            // [128 slots][2 o][49]
  float* P1 = smem + 12544;
  if (cg == 1) {
#pragma unroll
    for (int p = 0; p < NPOS; ++p) { P0[(slot * 2 + 0) * NPOS + p] = acc0[p]; P0[(slot * 2 + 1) * NPOS + p] = acc1[p]; }
  }
  if (cg == 3) {
#pragma unroll
    for (int p = 0; p < NPOS; ++p) { P1[(slot * 2 + 0) * NPOS + p] = acc0[p]; P1[(slot * 2 + 1) * NPOS + p] = acc1[p]; }
  }
  __syncthreads();
  if (cg == 0) {
#pragma unroll
    for (int p = 0; p < NPOS; ++p) { acc0[p] += P0[(slot * 2 + 0) * NPOS + p]; acc1[p] += P0[(slot * 2 + 1) * NPOS + p]; }
  }
  if (cg == 2) {
#pragma unroll
    for (int p = 0; p < NPOS; ++p) { acc0[p] += P1[(slot * 2 + 0) * NPOS + p]; acc1[p] += P1[(slot * 2 + 1) * NPOS + p]; }
  }
  __syncthreads();
  if (cg == 2) {
#pragma unroll
    for (int p = 0; p < NPOS; ++p) { P0[(slot * 2 + 0) * NPOS + p] = acc0[p]; P0[(slot * 2 + 1) * NPOS + p] = acc1[p]; }
  }
  __syncthreads();
  if (cg == 0) {
    float sc0 = gg[o0] / sqrtf(var[o0] + 1e-5f);
    float ad0 = (bias[o0] - mu[o0]) * sc0 + be[o0];
    float sc1 = gg[o1] / sqrtf(var[o1] + 1e-5f);
    float ad1 = (bias[o1] - mu[o1]) * sc1 + be[o1];
#pragma unroll
    for (int p = 0; p < NPOS; ++p) {
      float v0 = (acc0[p] + P0[(slot * 2 + 0) * NPOS + p]) * sc0 + ad0;
      float v1 = (acc1[p] + P0[(slot * 2 + 1) * NPOS + p]) * sc1 + ad1;
      P1[o0 * NPOS + p] = v0 > 0.f ? v0 : 0.f;   // final [256 o][49]
      P1[o1 * NPOS + p] = v1 > 0.f ? v1 : 0.f;
    }
  }
  __syncthreads();
  float* outb = out + (size_t)b * (256 * NPOS);
  for (int i = t; i < 256 * NPOS; i += 512) outb[i] = P1[i];
}

// ---------------------------------------------------------------------------
// conv 3x3 pad1 (256 -> 256) + bias + BN + ReLU.  Grid = B.
// 512 thr = 128 slots x 4-way K-split; thread computes o = slot and slot+128.
// Single-phase LDS tile [256][9][12] = 110,592 B -> 1 block/CU.
// Weights k-contiguous [c][o][12]: 3 b128 loads per (c,o), prefetched 1 ch ahead.
// ---------------------------------------------------------------------------
#define LOADROW(dst, base, rr)                                          \
  do {                                                                  \
    const float4* q4_ = (const float4*)((base) + (rr) * 12);            \
    float4 q0_ = q4_[0], q1_ = q4_[1], q2_ = q4_[2];                    \
    dst[0] = q0_.x; dst[1] = q0_.y; dst[2] = q0_.z; dst[3] = q0_.w;     \
    dst[4] = q1_.x; dst[5] = q1_.y; dst[6] = q1_.z; dst[7] = q1_.w;     \
    dst[8] = q2_.x;                                                     \
  } while (0)

__global__ __launch_bounds__(512, 1) void conv3x3_bn(
    const float* __restrict__ in, const float* __restrict__ wt,
    const float* __restrict__ bias, const float* __restrict__ gg,
    const float* __restrict__ be, const float* __restrict__ mu,
    const float* __restrict__ var, float* __restrict__ out) {
  __shared__ float smem[256 * 108];  // 110,592 B
  const int b = blockIdx.x, t = threadIdx.x;
  const int slot = t & 127, cg = t >> 7;   // cg in 0..3
  const int o0 = slot, o1 = slot + 128;
  const float* inb = in + (size_t)b * (256 * NPOS);
  float4* z4 = (float4*)smem;
  for (int i = t; i < 6912; i += 512) z4[i] = make_float4(0.f, 0.f, 0.f, 0.f);
  const int c0 = cg * 64;
  const float4* wv4 = (const float4*)wt;   // [(c*256+o)*3] float4s
  float4 wa0 = wv4[(c0 * 256 + o0) * 3 + 0];  // first-channel weights: issue
  float4 wa1 = wv4[(c0 * 256 + o0) * 3 + 1];  // before staging to overlap
  float4 wa2 = wv4[(c0 * 256 + o0) * 3 + 2];
  float4 wb0 = wv4[(c0 * 256 + o1) * 3 + 0];
  float4 wb1 = wv4[(c0 * 256 + o1) * 3 + 1];
  float4 wb2 = wv4[(c0 * 256 + o1) * 3 + 2];
  __syncthreads();  // zero done
  for (int i = t; i < 256 * NPOS; i += 512) {
    int c = i / NPOS, p = i - c * NPOS, y = p / 7, x = p - y * 7;
    smem[c * 108 + (y + 1) * 12 + (x + 1)] = inb[i];
  }
  float acc0[NPOS], acc1[NPOS];
#pragma unroll
  for (int p = 0; p < NPOS; ++p) { acc0[p] = 0.f; acc1[p] = 0.f; }
  __syncthreads();
  for (int cl = 0; cl < 64; ++cl) {
    const int c = c0 + cl;
    const int cn = (cl + 1 < 64) ? c + 1 : c;
    float4 na0 = wv4[(cn * 256 + o0) * 3 + 0];  // prefetch next channel
    float4 na1 = wv4[(cn * 256 + o0) * 3 + 1];
    float4 na2 = wv4[(cn * 256 + o0) * 3 + 2];
    float4 nb0 = wv4[(cn * 256 + o1) * 3 + 0];
    float4 nb1 = wv4[(cn * 256 + o1) * 3 + 1];
    float4 nb2 = wv4[(cn * 256 + o1) * 3 + 2];
    const float* tb = smem + c * 108;
    float R[3][9];
    LOADROW(R[0], tb, 0);
    LOADROW(R[1], tb, 1);
#pragma unroll
    for (int y = 0; y < 7; ++y) {
      LOADROW(R[(y + 2) % 3], tb, y + 2);
      const float* r0 = R[y % 3];
      const float* r1 = R[(y + 1) % 3];
      const float* r2 = R[(y + 2) % 3];
#pragma unroll
      for (int x = 0; x < 7; ++x) {
        float s0 = acc0[y * 7 + x];
        s0 = fmaf(wa0.x, r0[x],     s0);
        s0 = fmaf(wa0.y, r0[x + 1], s0);
        s0 = fmaf(wa0.z, r0[x + 2], s0);
        s0 = fmaf(wa0.w, r1[x],     s0);
        s0 = fmaf(wa1.x, r1[x + 1], s0);
        s0 = fmaf(wa1.y, r1[x + 2], s0);
        s0 = fmaf(wa1.z, r2[x],     s0);
        s0 = fmaf(wa1.w, r2[x + 1], s0);
        s0 = fmaf(wa2.x, r2[x + 2], s0);
        acc0[y * 7 + x] = s0;
        float s1 = acc1[y * 7 + x];
        s1 = fmaf(wb0.x, r0[x],     s1);
        s1 = fmaf(wb0.y, r0[x + 1], s1);
        s1 = fmaf(wb0.z, r0[x + 2], s1);
        s1 = fmaf(wb0.w, r1[x],     s1);
        s1 = fmaf(wb1.x, r1[x + 1], s1);
        s1 = fmaf(wb1.y, r1[x + 2], s1);
        s1 = fmaf(wb1.z, r2[x],     s1);
        s1 = fmaf(wb1.w, r2[x + 1], s1);
        s1 = fmaf(wb2.x, r2[x + 2], s1);
        acc1[y * 7 + x] = s1;
      }
    }
    wa0 = na0; wa1 = na1; wa2 = na2;
    wb0 = nb0; wb1 = nb1; wb2 = nb2;
  }
  __syncthreads();
  float* P0 = smem;            // [128 slots][2 o][49]
  float* P1 = smem + 12544;
  if (cg == 1) {
#pragma unroll
    for (int p = 0; p < NPOS; ++p) { P0[(slot * 2 + 0) * NPOS + p] = acc0[p]; P0[(slot * 2 + 1) * NPOS + p] = acc1[p]; }
  }
  if (cg == 3) {
#pragma unroll
    for (int p = 0; p < NPOS; ++p) { P1[(slot * 2 + 0) * NPOS + p] = acc0[p]; P1[(slot * 2 + 1) * NPOS + p] = acc1[p]; }
  }
  __syncthreads();
  if (cg == 0) {
#pragma unroll
    for (int p = 0; p < NPOS; ++p) { acc0[p] += P0[(slot * 2 + 0) * NPOS + p]; acc1[p] += P0[(slot * 2 + 1) * NPOS + p]; }
  }
  if (cg == 2) {
#pragma unroll
    for (int p = 0; p < NPOS; ++p) { acc0[p] += P1[(slot * 2 + 0) * NPOS + p]; acc1[p] += P1[(slot * 2 + 1) * NPOS + p]; }
  }
  __syncthreads();
  if (cg == 2) {
#pragma unroll
    for (int p = 0; p < NPOS; ++p) { P0[(slot * 2 + 0) * NPOS + p] = acc0[p]; P0[(slot * 2 + 1) * NPOS + p] = acc1[p]; }
  }
  __syncthreads();
  if (cg == 0) {
    float sc0 = gg[o0] / sqrtf(var[o0] + 1e-5f);
    float ad0 = (bias[o0] - mu[o0]) * sc0 + be[o0];
    float sc1 = gg[o1] / sqrtf(var[o1] + 1e-5f);
    float ad1 = (bias[o1] - mu[o1]) * sc1 + be[o1];
#pragma unroll
    for (int p = 0; p < NPOS; ++p) {
      float v0 = (acc0[p] + P0[(slot * 2 + 0) * NPOS + p]) * sc0 + ad0;
      float v1 = (acc1[p] + P0[(slot * 2 + 1) * NPOS + p]) * sc1 + ad1;
      P1[o0 * NPOS + p] = v0 > 0.f ? v0 : 0.f;   // final [256 o][49]
      P1[o1 * NPOS + p] = v1 > 0.f ? v1 : 0.f;
    }
  }
  __syncthreads();
  float* outb = out + (size_t)b * (256 * NPOS);
  for (int i = t; i < 256 * NPOS; i += 512) outb[i] = P1[i];
}

// ---------------------------------------------------------------------------
// Heads (box 48ch + cls 12ch, 3x3 pad1) + decode + sigmoid.
// 512 threads: 60 out-ch x 8-way K-split.  Weights prefetched one ch ahead.
// ---------------------------------------------------------------------------
__global__ __launch_bounds__(512, 2) void heads_decode(
    const float* __restrict__ in, const float* __restrict__ wbt,
    const float* __restrict__ wct, const float* __restrict__ bb,
    const float* __restrict__ bc, float* __restrict__ BXg,
    float* __restrict__ SCg) {
  __shared__ float smem[256 * 108];
  const int b = blockIdx.x, t = threadIdx.x;
  for (int i = t; i < 256 * 108; i += 512) smem[i] = 0.f;
  __syncthreads();
  const float* inb = in + (size_t)b * (256 * NPOS);
  for (int i = t; i < 256 * NPOS; i += 512) {
    int c = i / NPOS, p = i - c * NPOS, y = p / 7, x = p - y * 7;
    smem[c * 108 + (y + 1) * 12 + (x + 1)] = inb[i];
  }
  __syncthreads();
  float acc[NPOS];
#pragma unroll
  for (int p = 0; p < NPOS; ++p) acc[p] = 0.f;
  int o = 0, cg = 0;
  if (t < 480) {
    o = t % 60; cg = t / 60;  // 8-way K-split, 32 c each
    const float* wbase; int wstr;
    if (o < 48) { wbase = wbt + o; wstr = 48; }
    else        { wbase = wct + (o - 48); wstr = 12; }
    const int c0 = cg * 32;
    float wc_[9];
#pragma unroll
    for (int k = 0; k < 9; ++k) wc_[k] = wbase[(c0 * 9 + k) * wstr];
    for (int c = c0; c < c0 + 32; ++c) {
      int cn = (c + 1 < c0 + 32) ? c + 1 : c;
      float wn_[9];
#pragma unroll
      for (int k = 0; k < 9; ++k) wn_[k] = wbase[(cn * 9 + k) * wstr];  // prefetch
      const float* tb = smem + c * 108;
      float R[3][9];
      LOADROW(R[0], tb, 0);
      LOADROW(R[1], tb, 1);
#pragma unroll
      for (int y = 0; y < 7; ++y) {
        LOADROW(R[(y + 2) % 3], tb, y + 2);
        const float* r0 = R[y % 3];
        const float* r1 = R[(y + 1) % 3];
        const float* r2 = R[(y + 2) % 3];
#pragma unroll
        for (int x = 0; x < 7; ++x) {
          float s = acc[y * 7 + x];
          s = fmaf(wc_[0], r0[x], s);
          s = fmaf(wc_[1], r0[x + 1], s);
          s = fmaf(wc_[2], r0[x + 2], s);
          s = fmaf(wc_[3], r1[x], s);
          s = fmaf(wc_[4], r1[x + 1], s);
          s = fmaf(wc_[5], r1[x + 2], s);
          s = fmaf(wc_[6], r2[x], s);
          s = fmaf(wc_[7], r2[x + 1], s);
          s = fmaf(wc_[8], r2[x + 2], s);
          acc[y * 7 + x] = s;
        }
      }
#pragma unroll
      for (int k = 0; k < 9; ++k) wc_[k] = wn_[k];
    }
  }
  __syncthreads();
  float* part = smem;            // [7][60][49]
  float* H = smem + 7 * 2940;    // [60][49]
  if (t < 480 && cg > 0) {
#pragma unroll
    for (int p = 0; p < NPOS; ++p) part[(cg - 1) * 2940 + o * NPOS + p] = acc[p];
  }
  __syncthreads();
  if (t < 60) {  // cg == 0
    float bsum = (o < 48) ? bb[o] : bc[o - 48];
#pragma unroll
    for (int p = 0; p < NPOS; ++p) {
      float v = acc[p] + bsum;
      for (int g = 0; g < 7; ++g) v += part[g * 2940 + o * NPOS + p];
      H[o * NPOS + p] = v;
    }
  }
  __syncthreads();
  const float scl[4] = {0.3f, 0.5f, 0.7f, 0.9f};
  const float rat[3] = {0.7f, 1.0f, 1.3f};
  for (int n = t; n < NANCH; n += 512) {
    int p = n / 12, a = n - p * 12;
    int ph = p / 7, pw = p - ph * 7;
    float cx = (ph + 0.5f) / 7.0f;
    float cy = (pw + 0.5f) / 7.0f;
    int s = a / 3, r = a - s * 3;
    float rt = sqrtf(rat[r]);
    float wsz = scl[s] * rt, hsz = scl[s] / rt;
    float x1 = cx + (-wsz) * 0.5f, y1 = cy + (-hsz) * 0.5f;
    float x2 = cx + wsz * 0.5f,    y2 = cy + hsz * 0.5f;
    float acx = (x1 + x2) * 0.5f,  acy = (y1 + y2) * 0.5f;
    float asx = x2 - x1,           asy = y2 - y1;
    float bp0 = H[(a * 4 + 0) * NPOS + p];
    float bp1 = H[(a * 4 + 1) * NPOS + p];
    float bp2 = H[(a * 4 + 2) * NPOS + p];
    float bp3 = H[(a * 4 + 3) * NPOS + p];
    float pcx = bp0 * asx + acx;
    float pcy = bp1 * asy + acy;
    float psx = expf(bp2) * asx;
    float psy = expf(bp3) * asy;
    float* bx = BXg + (size_t)b * (NANCH * 4) + n * 4;
    bx[0] = pcx - psx * 0.5f;
    bx[1] = pcy - psy * 0.5f;
    bx[2] = pcx + psx * 0.5f;
    bx[3] = pcy + psy * 0.5f;
    float lg = H[(48 + a) * NPOS + p];
    SCg[(size_t)b * NANCH + n] = 1.0f / (1.0f + expf(-lg));
  }
}

// ---------------------------------------------------------------------------
// NMS: rank sort + IoU bitmask + wave-parallel greedy scan.  512 thr, 66 KB.
// ---------------------------------------------------------------------------
__device__ inline unsigned long long shfl64(unsigned long long v, int lane) {
  int lo = __shfl((int)(unsigned)(v & 0xffffffffULL), lane, 64);
  int hi = __shfl((int)(unsigned)(v >> 32), lane, 64);
  return ((unsigned long long)(unsigned)hi << 32) | (unsigned)lo;
}

__global__ __launch_bounds__(512, 4) void nms_kernel(
    const float* __restrict__ BXg, const float* __restrict__ SCg,
    float* __restrict__ out) {
  __shared__ float smem[16576];
  unsigned long long* KEY = (unsigned long long*)smem;          // [588]
  float* SB  = smem + 1176;                                     // [588*4]
  float* SSc = smem + 3528;                                     // [588]
  float* AR  = smem + 4116;                                     // [588]
  unsigned long long* ADJ = (unsigned long long*)(smem + 4704); // [588*10]
  int* KEEP = (int*)(smem + 16464);                             // [100]
  int* CNT  = (int*)(smem + 16564);
  const int b = blockIdx.x, t = threadIdx.x;
  const float* scb = SCg + (size_t)b * NANCH;
  const float4* bxb = (const float4*)(BXg + (size_t)b * (NANCH * 4));
  for (int i = t; i < NANCH; i += 512) {
    unsigned u = __float_as_uint(scb[i]);
    u = (u & 0x80000000u) ? ~u : (u | 0x80000000u);
    u = ~u;
    KEY[i] = ((unsigned long long)u << 32) | (unsigned)i;
  }
  __syncthreads();
  for (int i = t; i < NANCH; i += 512) {
    unsigned long long k = KEY[i];
    int rank = 0;
    for (int j = 0; j < NANCH; ++j) rank += (KEY[j] < k) ? 1 : 0;
    float4 bx = bxb[i];
    ((float4*)SB)[rank] = bx;
    SSc[rank] = scb[i];
    AR[rank] = (bx.z - bx.x) * (bx.w - bx.y);
  }
  __syncthreads();
  const float4* SB4 = (const float4*)SB;
  for (int task = t; task < NANCH * 10; task += 512) {
    int i = task % NANCH, w = task / NANCH;
    float4 a = SB4[i];
    float aar = AR[i];
    int jbase = w * 64;
    int jend = NANCH - jbase; if (jend > 64) jend = 64;
    unsigned long long bits = 0;
    for (int bi = 0; bi < jend; ++bi) {
      int j = jbase + bi;
      float4 bb = SB4[j];
      float ltx = fmaxf(a.x, bb.x), lty = fmaxf(a.y, bb.y);
      float rbx = fminf(a.z, bb.z), rby = fminf(a.w, bb.w);
      float wx = rbx - ltx; wx = wx > 0.f ? wx : 0.f;
      float wy = rby - lty; wy = wy > 0.f ? wy : 0.f;
      float inter = wx * wy;
      float iou = inter / (aar + AR[j] - inter + 1e-9f);
      if (iou > 0.5f) bits |= (1ULL << bi);
    }
    ADJ[i * 10 + w] = bits;
  }
  __syncthreads();
  if (t < 64) {
    unsigned long long valid = 0, supp = 0;
    if (t < 10) {
      int jbase = t * 64;
      int jend = NANCH - jbase; if (jend > 64) jend = 64;
      for (int k = 0; k < jend; ++k)
        valid |= (unsigned long long)(SSc[jbase + k] > 0.3f ? 1 : 0) << k;
    }
    int cnt = 0;
    for (int w = 0; w < 10 && cnt < 100; ++w) {
      unsigned long long cur = shfl64(valid, w) & ~shfl64(supp, w);
      while (cur && cnt < 100) {
        int bpos = (int)__builtin_ctzll(cur);
        int i = w * 64 + bpos;
        if (t == 0) KEEP[cnt] = i;
        cnt++;
        unsigned long long a = (t < 10) ? ADJ[i * 10 + t] : 0ULL;
        if (t < w) a = 0ULL;
        else if (t == w) a &= ~((2ULL << bpos) - 1ULL);
        supp |= a;
        unsigned long long aw = shfl64(a, w);
        cur &= ~aw;
        cur &= ~(1ULL << bpos);
      }
    }
    if (t == 0) *CNT = cnt;
  }
  __syncthreads();
  int cnt = *CNT;
  if (t < 100) {
    float4 bx = make_float4(0.f, 0.f, 0.f, 0.f);
    float s = 0.f, vld = 0.f;
    if (t < cnt) {
      int i = KEEP[t];
      bx = SB4[i];
      s = SSc[i];
      vld = 1.f;
    }
    float* ob = out + (size_t)b * 600 + t * 6;
    ob[0] = bx.x; ob[1] = bx.y; ob[2] = bx.z; ob[3] = bx.w;
    ob[4] = s;    ob[5] = vld;
  }
}

// ---------------------------------------------------------------------------
extern "C" void kernel_launch(void* const* d_in, const int* in_sizes, int n_in,
                              void* d_out, int out_size, void* d_ws, size_t ws_size,
                              hipStream_t stream) {
  const float* feat = (const float*)d_in[0];
  const float* w1  = (const float*)d_in[1];
  const float* b1  = (const float*)d_in[2];
  const float* g1  = (const float*)d_in[3];
  const float* be1 = (const float*)d_in[4];
  const float* mu1 = (const float*)d_in[5];
  const float* v1  = (const float*)d_in[6];
  const float* w2  = (const float*)d_in[7];
  const float* b2  = (const float*)d_in[8];
  const float* g2  = (const float*)d_in[9];
  const float* be2 = (const float*)d_in[10];
  const float* mu2 = (const float*)d_in[11];
  const float* v2  = (const float*)d_in[12];
  const float* w3  = (const float*)d_in[13];
  const float* b3  = (const float*)d_in[14];
  const float* g3  = (const float*)d_in[15];
  const float* be3 = (const float*)d_in[16];
  const float* mu3 = (const float*)d_in[17];
  const float* v3  = (const float*)d_in[18];
  const float* w4  = (const float*)d_in[19];
  const float* b4  = (const float*)d_in[20];
  const float* g4  = (const float*)d_in[21];
  const float* be4 = (const float*)d_in[22];
  const float* mu4 = (const float*)d_in[23];
  const float* v4  = (const float*)d_in[24];
  const float* wcls = (const float*)d_in[25];
  const float* bcls = (const float*)d_in[26];
  const float* wbox = (const float*)d_in[27];
  const float* bbox = (const float*)d_in[28];

  const int B = in_sizes[0] / (512 * NPOS);
  float* ws  = (float*)d_ws;
  size_t xsz = (size_t)B * 256 * NPOS;
  float* xa  = ws;
  float* xb  = xa + xsz;
  float* w1t = xb + xsz;
  float* w2t = w1t + 131072;
  float* w3t = w2t + 786432;   // 256*256*12 (k-padded)
  float* w4t = w3t + 786432;
  float* wbt = w4t + 786432;
  float* wct = wbt + 110592;
  float* BXg = wct + 27648;
  float* SCg = BXg + (size_t)B * (NANCH * 4);

  transpose_all<<<(2038784 + 255) / 256, 256, 0, stream>>>(
      w1, w2, w3, w4, wbox, wcls, w1t, w2t, w3t, w4t, wbt, wct);
  conv1x1_bn<<<B, 512, 0, stream>>>(feat, w1t, b1, g1, be1, mu1, v1, xa);
  conv3x3_bn<<<B, 512, 0, stream>>>(xa, w2t, b2, g2, be2, mu2, v2, xb);
  conv3x3_bn<<<B, 512, 0, stream>>>(xb, w3t, b3, g3, be3, mu3, v3, xa);
  conv3x3_bn<<<B, 512, 0, stream>>>(xa, w4t, b4, g4, be4, mu4, v4, xb);
  heads_decode<<<B, 512, 0, stream>>>(xb, wbt, wct, bbox, bcls, BXg, SCg);
  nms_kernel<<<B, 512, 0, stream>>>(BXg, SCg, (float*)d_out);
}

// Round 7
// 848.650 us; speedup vs baseline: 2.7256x; 1.0557x over previous
//
#include <hip/hip_runtime.h>
#include <cmath>
#include <cstdint>

#define NPOS 49
#define NANCH 588

// ---------------------------------------------------------------------------
// Weight transposes.
// w1:  [256][512] -> float4-interleaved w1t[q*256+o][4] = w1[o][4q..4q+3]
// w2/3/4: [o][c][3][3] -> k-contiguous wNt[(c*256+o)*12 + k]  (k<9, pad 12)
// heads:  wbt[ck*48+o], wct[ck*12+o]
// ---------------------------------------------------------------------------
__global__ void transpose_all(
    const float* __restrict__ w1, const float* __restrict__ w2,
    const float* __restrict__ w3, const float* __restrict__ w4,
    const float* __restrict__ wb, const float* __restrict__ wc,
    float* __restrict__ w1t, float* __restrict__ w2t, float* __restrict__ w3t,
    float* __restrict__ w4t, float* __restrict__ wbt, float* __restrict__ wct) {
  int idx = blockIdx.x * blockDim.x + threadIdx.x;
  if (idx < 131072) {
    int o = idx / 512, c = idx % 512;
    w1t[((c >> 2) * 256 + o) * 4 + (c & 3)] = w1[idx];
    return;
  }
  idx -= 131072;
  if (idx < 589824) {
    int o = idx / 2304, ck = idx % 2304, c = ck / 9, k = ck - c * 9;
    w2t[(c * 256 + o) * 12 + k] = w2[idx]; return;
  }
  idx -= 589824;
  if (idx < 589824) {
    int o = idx / 2304, ck = idx % 2304, c = ck / 9, k = ck - c * 9;
    w3t[(c * 256 + o) * 12 + k] = w3[idx]; return;
  }
  idx -= 589824;
  if (idx < 589824) {
    int o = idx / 2304, ck = idx % 2304, c = ck / 9, k = ck - c * 9;
    w4t[(c * 256 + o) * 12 + k] = w4[idx]; return;
  }
  idx -= 589824;
  if (idx < 110592) { int o = idx / 2304, ck = idx % 2304; wbt[ck * 48 + o] = wb[idx]; return; }
  idx -= 110592;
  if (idx < 27648)  { int o = idx / 2304, ck = idx % 2304; wct[ck * 12 + o] = wc[idx]; return; }
}

// ---------------------------------------------------------------------------
// conv 1x1 (512 -> 256) + bias + BN + ReLU.  Grid = B (block = whole image).
// 512 thr = 128 slots x 4-way K-split; thread computes o = slot and slot+128.
// (unchanged from round 6)
// ---------------------------------------------------------------------------
__global__ __launch_bounds__(512, 1) void conv1x1_bn(
    const float* __restrict__ in, const float* __restrict__ wt_f,
    const float* __restrict__ bias, const float* __restrict__ gg,
    const float* __restrict__ be, const float* __restrict__ mu,
    const float* __restrict__ var, float* __restrict__ out) {
  __shared__ float smem[512 * 52];  // 106,496 B -> 1 block/CU
  const int b = blockIdx.x, t = threadIdx.x;
  const int slot = t & 127, cg = t >> 7;   // cg in 0..3
  const int o0 = slot, o1 = slot + 128;
  const float* inb = in + (size_t)b * (512 * NPOS);
  const float4* wq = (const float4*)wt_f;  // [128 quads][256 o]
  const int q0 = cg * 32;                  // 32 quads (128 channels) per cg
  float4 wca = wq[q0 * 256 + o0];          // issue before staging (overlap)
  float4 wcb = wq[q0 * 256 + o1];
  for (int i = t; i < 512 * NPOS; i += 512) {
    int c = i / NPOS, p = i - c * NPOS;
    smem[c * 52 + p] = inb[i];
  }
  float acc0[NPOS], acc1[NPOS];
#pragma unroll
  for (int p = 0; p < NPOS; ++p) { acc0[p] = 0.f; acc1[p] = 0.f; }
  __syncthreads();
  for (int q = q0; q < q0 + 32; ++q) {
    int nq = (q + 1 < q0 + 32) ? q + 1 : q;
    float4 wna = wq[nq * 256 + o0];        // prefetch next quad
    float4 wnb = wq[nq * 256 + o1];
#pragma unroll
    for (int j = 0; j < 4; ++j) {
      float wa = (j == 0) ? wca.x : (j == 1) ? wca.y : (j == 2) ? wca.z : wca.w;
      float wb2 = (j == 0) ? wcb.x : (j == 1) ? wcb.y : (j == 2) ? wcb.z : wcb.w;
      const float* row = smem + (q * 4 + j) * 52;
      const float4* tr = (const float4*)row;
#pragma unroll
      for (int jj = 0; jj < 12; ++jj) {
        float4 qv = tr[jj];
        acc0[4 * jj + 0] = fmaf(wa, qv.x, acc0[4 * jj + 0]);
        acc0[4 * jj + 1] = fmaf(wa, qv.y, acc0[4 * jj + 1]);
        acc0[4 * jj + 2] = fmaf(wa, qv.z, acc0[4 * jj + 2]);
        acc0[4 * jj + 3] = fmaf(wa, qv.w, acc0[4 * jj + 3]);
        acc1[4 * jj + 0] = fmaf(wb2, qv.x, acc1[4 * jj + 0]);
        acc1[4 * jj + 1] = fmaf(wb2, qv.y, acc1[4 * jj + 1]);
        acc1[4 * jj + 2] = fmaf(wb2, qv.z, acc1[4 * jj + 2]);
        acc1[4 * jj + 3] = fmaf(wb2, qv.w, acc1[4 * jj + 3]);
      }
      float s48 = row[48];
      acc0[48] = fmaf(wa, s48, acc0[48]);
      acc1[48] = fmaf(wb2, s48, acc1[48]);
    }
    wca = wna; wcb = wnb;
  }
  __syncthreads();
  float* P0 = smem;            // [128 slots][2 o][49]
  float* P1 = smem + 12544;
  if (cg == 1) {
#pragma unroll
    for (int p = 0; p < NPOS; ++p) { P0[(slot * 2 + 0) * NPOS + p] = acc0[p]; P0[(slot * 2 + 1) * NPOS + p] = acc1[p]; }
  }
  if (cg == 3) {
#pragma unroll
    for (int p = 0; p < NPOS; ++p) { P1[(slot * 2 + 0) * NPOS + p] = acc0[p]; P1[(slot * 2 + 1) * NPOS + p] = acc1[p]; }
  }
  __syncthreads();
  if (cg == 0) {
#pragma unroll
    for (int p = 0; p < NPOS; ++p) { acc0[p] += P0[(slot * 2 + 0) * NPOS + p]; acc1[p] += P0[(slot * 2 + 1) * NPOS + p]; }
  }
  if (cg == 2) {
#pragma unroll
    for (int p = 0; p < NPOS; ++p) { acc0[p] += P1[(slot * 2 + 0) * NPOS + p]; acc1[p] += P1[(slot * 2 + 1) * NPOS + p]; }
  }
  __syncthreads();
  if (cg == 2) {
#pragma unroll
    for (int p = 0; p < NPOS; ++p) { P0[(slot * 2 + 0) * NPOS + p] = acc0[p]; P0[(slot * 2 + 1) * NPOS + p] = acc1[p]; }
  }
  __syncthreads();
  if (cg == 0) {
    float sc0 = gg[o0] / sqrtf(var[o0] + 1e-5f);
    float ad0 = (bias[o0] - mu[o0]) * sc0 + be[o0];
    float sc1 = gg[o1] / sqrtf(var[o1] + 1e-5f);
    float ad1 = (bias[o1] - mu[o1]) * sc1 + be[o1];
#pragma unroll
    for (int p = 0; p < NPOS; ++p) {
      float v0 = (acc0[p] + P0[(slot * 2 + 0) * NPOS + p]) * sc0 + ad0;
      float v1 = (acc1[p] + P0[(slot * 2 + 1) * NPOS + p]) * sc1 + ad1;
      P1[o0 * NPOS + p] = v0 > 0.f ? v0 : 0.f;   // final [256 o][49]
      P1[o1 * NPOS + p] = v1 > 0.f ? v1 : 0.f;
    }
  }
  __syncthreads();
  float* outb = out + (size_t)b * (256 * NPOS);
  for (int i = t; i < 256 * NPOS; i += 512) outb[i] = P1[i];
}

// ---------------------------------------------------------------------------
// conv 3x3 pad1 (256 -> 256) + bias + BN + ReLU.
// Grid = 2*B: block = (image, o-half of 128).  512 thr = 128 slots x 4-way
// K-split (64-ch chains, same association as before).  COMPACT LDS tile
// [256][7][8] = 57,344 B -> 2 blocks/CU = 4 waves/SIMD.  Border rows with
// exactly-zero inputs are skipped (bit-identical; -10% FMA, 14 ds_read/ch).
// ---------------------------------------------------------------------------
#define LOADROW2(dst, base, yy)                                         \
  do {                                                                  \
    const float4* q4_ = (const float4*)((base) + (yy) * 8);             \
    float4 a_ = q4_[0], b_ = q4_[1];                                    \
    dst[0] = 0.f;                                                       \
    dst[1] = a_.x; dst[2] = a_.y; dst[3] = a_.z; dst[4] = a_.w;         \
    dst[5] = b_.x; dst[6] = b_.y; dst[7] = b_.z; dst[8] = b_.w;         \
  } while (0)

// 9-tap row-triple FMA for one output row (top/center/bottom in w-order 0..8)
#define FMA9(accbase, rt, rc, rb)                                       \
  do {                                                                  \
    _Pragma("unroll")                                                   \
    for (int x = 0; x < 7; ++x) {                                       \
      float s = acc[(accbase) + x];                                     \
      s = fmaf(wa0.x, rt[x],     s);                                    \
      s = fmaf(wa0.y, rt[x + 1], s);                                    \
      s = fmaf(wa0.z, rt[x + 2], s);                                    \
      s = fmaf(wa0.w, rc[x],     s);                                    \
      s = fmaf(wa1.x, rc[x + 1], s);                                    \
      s = fmaf(wa1.y, rc[x + 2], s);                                    \
      s = fmaf(wa1.z, rb[x],     s);                                    \
      s = fmaf(wa1.w, rb[x + 1], s);                                    \
      s = fmaf(wa2.x, rb[x + 2], s);                                    \
      acc[(accbase) + x] = s;                                           \
    }                                                                   \
  } while (0)

__global__ __launch_bounds__(512, 2) void conv3x3_bn(
    const float* __restrict__ in, const float* __restrict__ wt,
    const float* __restrict__ bias, const float* __restrict__ gg,
    const float* __restrict__ be, const float* __restrict__ mu,
    const float* __restrict__ var, float* __restrict__ out) {
  __shared__ float smem[256 * 56];  // compact [c][7][8], 57,344 B
  const int blk = blockIdx.x, t = threadIdx.x;
  const int b = blk >> 1, oh = blk & 1;
  const int slot = t & 127, cg = t >> 7;   // cg in 0..3, 64-ch chains
  const int og = oh * 128 + slot;
  const float* inb = in + (size_t)b * (256 * NPOS);
  float4* z4 = (float4*)smem;
  for (int i = t; i < 3584; i += 512) z4[i] = make_float4(0.f, 0.f, 0.f, 0.f);
  const int c0 = cg * 64;
  const float4* wv4 = (const float4*)wt;   // [(c*256+o)*3] float4s
  float4 wa0 = wv4[(c0 * 256 + og) * 3 + 0];  // first-channel weights: issue
  float4 wa1 = wv4[(c0 * 256 + og) * 3 + 1];  // before staging to overlap
  float4 wa2 = wv4[(c0 * 256 + og) * 3 + 2];
  __syncthreads();  // zero done
  for (int i = t; i < 256 * NPOS; i += 512) {
    int c = i / NPOS, p = i - c * NPOS, y = p / 7, x = p - y * 7;
    smem[c * 56 + y * 8 + x] = inb[i];     // x=7 column stays 0
  }
  float acc[NPOS];
#pragma unroll
  for (int p = 0; p < NPOS; ++p) acc[p] = 0.f;
  __syncthreads();
  for (int cl = 0; cl < 64; ++cl) {
    const int c = c0 + cl;
    const int cn = (cl + 1 < 64) ? c + 1 : c;
    float4 na0 = wv4[(cn * 256 + og) * 3 + 0];  // prefetch next channel
    float4 na1 = wv4[(cn * 256 + og) * 3 + 1];
    float4 na2 = wv4[(cn * 256 + og) * 3 + 2];
    const float* tb = smem + c * 56;
    float R0[9], R1[9], R2[9];
    LOADROW2(R0, tb, 0);
    LOADROW2(R1, tb, 1);
    // y=0: rows 0 (w3..5), 1 (w6..8) — top row is exactly zero, skipped
#pragma unroll
    for (int x = 0; x < 7; ++x) {
      float s = acc[x];
      s = fmaf(wa0.w, R0[x],     s);
      s = fmaf(wa1.x, R0[x + 1], s);
      s = fmaf(wa1.y, R0[x + 2], s);
      s = fmaf(wa1.z, R1[x],     s);
      s = fmaf(wa1.w, R1[x + 1], s);
      s = fmaf(wa2.x, R1[x + 2], s);
      acc[x] = s;
    }
    LOADROW2(R2, tb, 2);
    FMA9(7, R0, R1, R2);       // y=1: rows 0,1,2
    LOADROW2(R0, tb, 3);
    FMA9(14, R1, R2, R0);      // y=2: rows 1,2,3
    LOADROW2(R1, tb, 4);
    FMA9(21, R2, R0, R1);      // y=3: rows 2,3,4
    LOADROW2(R2, tb, 5);
    FMA9(28, R0, R1, R2);      // y=4: rows 3,4,5
    LOADROW2(R0, tb, 6);
    FMA9(35, R1, R2, R0);      // y=5: rows 4,5,6
    // y=6: rows 5 (w0..2), 6 (w3..5) — bottom row is exactly zero, skipped
#pragma unroll
    for (int x = 0; x < 7; ++x) {
      float s = acc[42 + x];
      s = fmaf(wa0.x, R2[x],     s);
      s = fmaf(wa0.y, R2[x + 1], s);
      s = fmaf(wa0.z, R2[x + 2], s);
      s = fmaf(wa0.w, R0[x],     s);
      s = fmaf(wa1.x, R0[x + 1], s);
      s = fmaf(wa1.y, R0[x + 2], s);
      acc[42 + x] = s;
    }
    wa0 = na0; wa1 = na1; wa2 = na2;
  }
  __syncthreads();
  float* P0 = smem;            // [128 slots][49]
  float* P1 = smem + 6272;
  if (cg == 1) { for (int p = 0; p < NPOS; ++p) P0[slot * NPOS + p] = acc[p]; }
  if (cg == 3) { for (int p = 0; p < NPOS; ++p) P1[slot * NPOS + p] = acc[p]; }
  __syncthreads();
  if (cg == 0) { for (int p = 0; p < NPOS; ++p) acc[p] += P0[slot * NPOS + p]; }
  if (cg == 2) { for (int p = 0; p < NPOS; ++p) acc[p] += P1[slot * NPOS + p]; }
  __syncthreads();
  if (cg == 2) { for (int p = 0; p < NPOS; ++p) P0[slot * NPOS + p] = acc[p]; }
  __syncthreads();
  if (cg == 0) {
    float scale = gg[og] / sqrtf(var[og] + 1e-5f);
    float add = (bias[og] - mu[og]) * scale + be[og];
#pragma unroll
    for (int p = 0; p < NPOS; ++p) {
      float v = (acc[p] + P0[slot * NPOS + p]) * scale + add;
      P1[slot * NPOS + p] = v > 0.f ? v : 0.f;   // final [128 o][49]
    }
  }
  __syncthreads();
  float* outb = out + (size_t)b * (256 * NPOS) + oh * (128 * NPOS);
  for (int i = t; i < 128 * NPOS; i += 512) outb[i] = P1[i];
}

// ---------------------------------------------------------------------------
// Heads (box 48ch + cls 12ch, 3x3 pad1) + decode + sigmoid.
// 512 threads: 60 out-ch x 8-way K-split.  (unchanged from round 6)
// ---------------------------------------------------------------------------
#define LOADROW(dst, base, rr)                                          \
  do {                                                                  \
    const float4* q4_ = (const float4*)((base) + (rr) * 12);            \
    float4 q0_ = q4_[0], q1_ = q4_[1], q2_ = q4_[2];                    \
    dst[0] = q0_.x; dst[1] = q0_.y; dst[2] = q0_.z; dst[3] = q0_.w;     \
    dst[4] = q1_.x; dst[5] = q1_.y; dst[6] = q1_.z; dst[7] = q1_.w;     \
    dst[8] = q2_.x;                                                     \
  } while (0)

__global__ __launch_bounds__(512, 2) void heads_decode(
    const float* __restrict__ in, const float* __restrict__ wbt,
    const float* __restrict__ wct, const float* __restrict__ bb,
    const float* __restrict__ bc, float* __restrict__ BXg,
    float* __restrict__ SCg) {
  __shared__ float smem[256 * 108];
  const int b = blockIdx.x, t = threadIdx.x;
  for (int i = t; i < 256 * 108; i += 512) smem[i] = 0.f;
  __syncthreads();
  const float* inb = in + (size_t)b * (256 * NPOS);
  for (int i = t; i < 256 * NPOS; i += 512) {
    int c = i / NPOS, p = i - c * NPOS, y = p / 7, x = p - y * 7;
    smem[c * 108 + (y + 1) * 12 + (x + 1)] = inb[i];
  }
  __syncthreads();
  float acc[NPOS];
#pragma unroll
  for (int p = 0; p < NPOS; ++p) acc[p] = 0.f;
  int o = 0, cg = 0;
  if (t < 480) {
    o = t % 60; cg = t / 60;  // 8-way K-split, 32 c each
    const float* wbase; int wstr;
    if (o < 48) { wbase = wbt + o; wstr = 48; }
    else        { wbase = wct + (o - 48); wstr = 12; }
    const int c0 = cg * 32;
    float wc_[9];
#pragma unroll
    for (int k = 0; k < 9; ++k) wc_[k] = wbase[(c0 * 9 + k) * wstr];
    for (int c = c0; c < c0 + 32; ++c) {
      int cn = (c + 1 < c0 + 32) ? c + 1 : c;
      float wn_[9];
#pragma unroll
      for (int k = 0; k < 9; ++k) wn_[k] = wbase[(cn * 9 + k) * wstr];  // prefetch
      const float* tb = smem + c * 108;
      float R[3][9];
      LOADROW(R[0], tb, 0);
      LOADROW(R[1], tb, 1);
#pragma unroll
      for (int y = 0; y < 7; ++y) {
        LOADROW(R[(y + 2) % 3], tb, y + 2);
        const float* r0 = R[y % 3];
        const float* r1 = R[(y + 1) % 3];
        const float* r2 = R[(y + 2) % 3];
#pragma unroll
        for (int x = 0; x < 7; ++x) {
          float s = acc[y * 7 + x];
          s = fmaf(wc_[0], r0[x], s);
          s = fmaf(wc_[1], r0[x + 1], s);
          s = fmaf(wc_[2], r0[x + 2], s);
          s = fmaf(wc_[3], r1[x], s);
          s = fmaf(wc_[4], r1[x + 1], s);
          s = fmaf(wc_[5], r1[x + 2], s);
          s = fmaf(wc_[6], r2[x], s);
          s = fmaf(wc_[7], r2[x + 1], s);
          s = fmaf(wc_[8], r2[x + 2], s);
          acc[y * 7 + x] = s;
        }
      }
#pragma unroll
      for (int k = 0; k < 9; ++k) wc_[k] = wn_[k];
    }
  }
  __syncthreads();
  float* part = smem;            // [7][60][49]
  float* H = smem + 7 * 2940;    // [60][49]
  if (t < 480 && cg > 0) {
#pragma unroll
    for (int p = 0; p < NPOS; ++p) part[(cg - 1) * 2940 + o * NPOS + p] = acc[p];
  }
  __syncthreads();
  if (t < 60) {  // cg == 0
    float bsum = (o < 48) ? bb[o] : bc[o - 48];
#pragma unroll
    for (int p = 0; p < NPOS; ++p) {
      float v = acc[p] + bsum;
      for (int g = 0; g < 7; ++g) v += part[g * 2940 + o * NPOS + p];
      H[o * NPOS + p] = v;
    }
  }
  __syncthreads();
  const float scl[4] = {0.3f, 0.5f, 0.7f, 0.9f};
  const float rat[3] = {0.7f, 1.0f, 1.3f};
  for (int n = t; n < NANCH; n += 512) {
    int p = n / 12, a = n - p * 12;
    int ph = p / 7, pw = p - ph * 7;
    float cx = (ph + 0.5f) / 7.0f;
    float cy = (pw + 0.5f) / 7.0f;
    int s = a / 3, r = a - s * 3;
    float rt = sqrtf(rat[r]);
    float wsz = scl[s] * rt, hsz = scl[s] / rt;
    float x1 = cx + (-wsz) * 0.5f, y1 = cy + (-hsz) * 0.5f;
    float x2 = cx + wsz * 0.5f,    y2 = cy + hsz * 0.5f;
    float acx = (x1 + x2) * 0.5f,  acy = (y1 + y2) * 0.5f;
    float asx = x2 - x1,           asy = y2 - y1;
    float bp0 = H[(a * 4 + 0) * NPOS + p];
    float bp1 = H[(a * 4 + 1) * NPOS + p];
    float bp2 = H[(a * 4 + 2) * NPOS + p];
    float bp3 = H[(a * 4 + 3) * NPOS + p];
    float pcx = bp0 * asx + acx;
    float pcy = bp1 * asy + acy;
    float psx = expf(bp2) * asx;
    float psy = expf(bp3) * asy;
    float* bx = BXg + (size_t)b * (NANCH * 4) + n * 4;
    bx[0] = pcx - psx * 0.5f;
    bx[1] = pcy - psy * 0.5f;
    bx[2] = pcx + psx * 0.5f;
    bx[3] = pcy + psy * 0.5f;
    float lg = H[(48 + a) * NPOS + p];
    SCg[(size_t)b * NANCH + n] = 1.0f / (1.0f + expf(-lg));
  }
}

// ---------------------------------------------------------------------------
// NMS: rank sort + IoU bitmask + wave-parallel greedy scan.  512 thr, 66 KB.
// ---------------------------------------------------------------------------
__device__ inline unsigned long long shfl64(unsigned long long v, int lane) {
  int lo = __shfl((int)(unsigned)(v & 0xffffffffULL), lane, 64);
  int hi = __shfl((int)(unsigned)(v >> 32), lane, 64);
  return ((unsigned long long)(unsigned)hi << 32) | (unsigned)lo;
}

__global__ __launch_bounds__(512, 4) void nms_kernel(
    const float* __restrict__ BXg, const float* __restrict__ SCg,
    float* __restrict__ out) {
  __shared__ float smem[16576];
  unsigned long long* KEY = (unsigned long long*)smem;          // [588]
  float* SB  = smem + 1176;                                     // [588*4]
  float* SSc = smem + 3528;                                     // [588]
  float* AR  = smem + 4116;                                     // [588]
  unsigned long long* ADJ = (unsigned long long*)(smem + 4704); // [588*10]
  int* KEEP = (int*)(smem + 16464);                             // [100]
  int* CNT  = (int*)(smem + 16564);
  const int b = blockIdx.x, t = threadIdx.x;
  const float* scb = SCg + (size_t)b * NANCH;
  const float4* bxb = (const float4*)(BXg + (size_t)b * (NANCH * 4));
  for (int i = t; i < NANCH; i += 512) {
    unsigned u = __float_as_uint(scb[i]);
    u = (u & 0x80000000u) ? ~u : (u | 0x80000000u);
    u = ~u;
    KEY[i] = ((unsigned long long)u << 32) | (unsigned)i;
  }
  __syncthreads();
  for (int i = t; i < NANCH; i += 512) {
    unsigned long long k = KEY[i];
    int rank = 0;
    for (int j = 0; j < NANCH; ++j) rank += (KEY[j] < k) ? 1 : 0;
    float4 bx = bxb[i];
    ((float4*)SB)[rank] = bx;
    SSc[rank] = scb[i];
    AR[rank] = (bx.z - bx.x) * (bx.w - bx.y);
  }
  __syncthreads();
  const float4* SB4 = (const float4*)SB;
  for (int task = t; task < NANCH * 10; task += 512) {
    int i = task % NANCH, w = task / NANCH;
    float4 a = SB4[i];
    float aar = AR[i];
    int jbase = w * 64;
    int jend = NANCH - jbase; if (jend > 64) jend = 64;
    unsigned long long bits = 0;
    for (int bi = 0; bi < jend; ++bi) {
      int j = jbase + bi;
      float4 bb = SB4[j];
      float ltx = fmaxf(a.x, bb.x), lty = fmaxf(a.y, bb.y);
      float rbx = fminf(a.z, bb.z), rby = fminf(a.w, bb.w);
      float wx = rbx - ltx; wx = wx > 0.f ? wx : 0.f;
      float wy = rby - lty; wy = wy > 0.f ? wy : 0.f;
      float inter = wx * wy;
      float iou = inter / (aar + AR[j] - inter + 1e-9f);
      if (iou > 0.5f) bits |= (1ULL << bi);
    }
    ADJ[i * 10 + w] = bits;
  }
  __syncthreads();
  if (t < 64) {
    unsigned long long valid = 0, supp = 0;
    if (t < 10) {
      int jbase = t * 64;
      int jend = NANCH - jbase; if (jend > 64) jend = 64;
      for (int k = 0; k < jend; ++k)
        valid |= (unsigned long long)(SSc[jbase + k] > 0.3f ? 1 : 0) << k;
    }
    int cnt = 0;
    for (int w = 0; w < 10 && cnt < 100; ++w) {
      unsigned long long cur = shfl64(valid, w) & ~shfl64(supp, w);
      while (cur && cnt < 100) {
        int bpos = (int)__builtin_ctzll(cur);
        int i = w * 64 + bpos;
        if (t == 0) KEEP[cnt] = i;
        cnt++;
        unsigned long long a = (t < 10) ? ADJ[i * 10 + t] : 0ULL;
        if (t < w) a = 0ULL;
        else if (t == w) a &= ~((2ULL << bpos) - 1ULL);
        supp |= a;
        unsigned long long aw = shfl64(a, w);
        cur &= ~aw;
        cur &= ~(1ULL << bpos);
      }
    }
    if (t == 0) *CNT = cnt;
  }
  __syncthreads();
  int cnt = *CNT;
  if (t < 100) {
    float4 bx = make_float4(0.f, 0.f, 0.f, 0.f);
    float s = 0.f, vld = 0.f;
    if (t < cnt) {
      int i = KEEP[t];
      bx = SB4[i];
      s = SSc[i];
      vld = 1.f;
    }
    float* ob = out + (size_t)b * 600 + t * 6;
    ob[0] = bx.x; ob[1] = bx.y; ob[2] = bx.z; ob[3] = bx.w;
    ob[4] = s;    ob[5] = vld;
  }
}

// ---------------------------------------------------------------------------
extern "C" void kernel_launch(void* const* d_in, const int* in_sizes, int n_in,
                              void* d_out, int out_size, void* d_ws, size_t ws_size,
                              hipStream_t stream) {
  const float* feat = (const float*)d_in[0];
  const float* w1  = (const float*)d_in[1];
  const float* b1  = (const float*)d_in[2];
  const float* g1  = (const float*)d_in[3];
  const float* be1 = (const float*)d_in[4];
  const float* mu1 = (const float*)d_in[5];
  const float* v1  = (const float*)d_in[6];
  const float* w2  = (const float*)d_in[7];
  const float* b2  = (const float*)d_in[8];
  const float* g2  = (const float*)d_in[9];
  const float* be2 = (const float*)d_in[10];
  const float* mu2 = (const float*)d_in[11];
  const float* v2  = (const float*)d_in[12];
  const float* w3  = (const float*)d_in[13];
  const float* b3  = (const float*)d_in[14];
  const float* g3  = (const float*)d_in[15];
  const float* be3 = (const float*)d_in[16];
  const float* mu3 = (const float*)d_in[17];
  const float* v3  = (const float*)d_in[18];
  const float* w4  = (const float*)d_in[19];
  const float* b4  = (const float*)d_in[20];
  const float* g4  = (const float*)d_in[21];
  const float* be4 = (const float*)d_in[22];
  const float* mu4 = (const float*)d_in[23];
  const float* v4  = (const float*)d_in[24];
  const float* wcls = (const float*)d_in[25];
  const float* bcls = (const float*)d_in[26];
  const float* wbox = (const float*)d_in[27];
  const float* bbox = (const float*)d_in[28];

  const int B = in_sizes[0] / (512 * NPOS);
  float* ws  = (float*)d_ws;
  size_t xsz = (size_t)B * 256 * NPOS;
  float* xa  = ws;
  float* xb  = xa + xsz;
  float* w1t = xb + xsz;
  float* w2t = w1t + 131072;
  float* w3t = w2t + 786432;   // 256*256*12 (k-padded)
  float* w4t = w3t + 786432;
  float* wbt = w4t + 786432;
  float* wct = wbt + 110592;
  float* BXg = wct + 27648;
  float* SCg = BXg + (size_t)B * (NANCH * 4);

  transpose_all<<<(2038784 + 255) / 256, 256, 0, stream>>>(
      w1, w2, w3, w4, wbox, wcls, w1t, w2t, w3t, w4t, wbt, wct);
  conv1x1_bn<<<B, 512, 0, stream>>>(feat, w1t, b1, g1, be1, mu1, v1, xa);
  conv3x3_bn<<<2 * B, 512, 0, stream>>>(xa, w2t, b2, g2, be2, mu2, v2, xb);
  conv3x3_bn<<<2 * B, 512, 0, stream>>>(xb, w3t, b3, g3, be3, mu3, v3, xa);
  conv3x3_bn<<<2 * B, 512, 0, stream>>>(xa, w4t, b4, g4, be4, mu4, v4, xb);
  heads_decode<<<B, 512, 0, stream>>>(xb, wbt, wct, bbox, bcls, BXg, SCg);
  nms_kernel<<<B, 512, 0, stream>>>(BXg, SCg, (float*)d_out);
}